// Round 1
// baseline (888.140 us; speedup 1.0000x reference)
//
#include <hip/hip_runtime.h>

constexpr int D  = 256;
constexpr int NH = 4;

// One block per sequence of length L. Computes:
//   q,k = x@Wq+bq, x@Wk+bk ; scores = q k^T/8 masked ; a = softmax(scores)
//   abar = sum_w m_w a_w ; z_h = abar_h @ x ; pp = z@Wv + cnt*bv
//   Out = (pp@Wo)/cnt + bo   (or exact 0 if cnt==0), MaskOut = cnt>0
// which equals masked_mean(MHA(x)) of the reference (pooling commuted
// through the PV product and the output projection; cnt+1e-10==cnt in fp32).
template<int L, typename MT>
__global__ __launch_bounds__(256, 1)
void mha_pool_kernel(const float* __restrict__ X,
                     const MT* __restrict__ Mask,
                     const float* __restrict__ Wq, const float* __restrict__ Wk,
                     const float* __restrict__ Wv, const float* __restrict__ Wo,
                     const float* __restrict__ bq, const float* __restrict__ bk,
                     const float* __restrict__ bv, const float* __restrict__ bo,
                     float* __restrict__ Out, float* __restrict__ MaskOut)
{
    constexpr int R   = L / 8;              // rows per thread in projections
    constexpr int P4  = 65;                 // float4 pitch of x/Q rows (260 dwords, breaks bank aliasing)
    constexpr int GRP = (L == 16) ? 16 : 8; // lanes per score row
    constexpr int CPT = (L == 64) ? 8 : 1;  // score cols per thread
    constexpr int RPT = (L == 64) ? 2 : 1;  // score rows per thread

    __shared__ float sX[L * P4 * 4];        // x, later K
    __shared__ float sQ[L * P4 * 4];
    __shared__ float sZ[NH][D];
    __shared__ float sAbar[NH][64];
    __shared__ float sPart[4][64];
    __shared__ float sM[64];
    __shared__ float sPP[D];
    __shared__ float sCnt;

    const int tid = threadIdx.x;
    const int seq = blockIdx.x;
    const float* Xs = X + (size_t)seq * L * D;

    float4* sX4 = (float4*)sX;
    float4* sQ4 = (float4*)sQ;
    const float4* X4 = (const float4*)Xs;

    if (tid < L) sM[tid] = (float)Mask[(size_t)seq * L + tid];
    for (int i = tid; i < L * 64; i += 256) {
        const int row = i >> 6, c4 = i & 63;
        sX4[row * P4 + c4] = X4[i];
    }
    __syncthreads();
    if (tid == 0) {
        float c = 0.f;
        for (int w = 0; w < L; ++w) c += sM[w];
        sCnt = c;
    }

    const int tn = tid & 31, tw = tid >> 5;
    const int n0 = tn * 8, w0 = tw * R;

    float acc[R][8];

    auto proj = [&](const float* __restrict__ W, const float* __restrict__ bias) {
        const float4* Wg4 = (const float4*)W;
        #pragma unroll
        for (int r = 0; r < R; ++r)
            #pragma unroll
            for (int c = 0; c < 8; ++c) acc[r][c] = bias[n0 + c];
        #pragma unroll 2
        for (int dq = 0; dq < 64; ++dq) {      // 4 d's per iter
            float4 xv[R];
            #pragma unroll
            for (int r = 0; r < R; ++r) xv[r] = sX4[(w0 + r) * P4 + dq];
            #pragma unroll
            for (int e = 0; e < 4; ++e) {
                const int d = dq * 4 + e;
                const float4 wv0 = Wg4[d * 64 + tn * 2];
                const float4 wv1 = Wg4[d * 64 + tn * 2 + 1];
                #pragma unroll
                for (int r = 0; r < R; ++r) {
                    const float xs = (e == 0) ? xv[r].x : (e == 1) ? xv[r].y
                                   : (e == 2) ? xv[r].z : xv[r].w;
                    acc[r][0] = fmaf(xs, wv0.x, acc[r][0]);
                    acc[r][1] = fmaf(xs, wv0.y, acc[r][1]);
                    acc[r][2] = fmaf(xs, wv0.z, acc[r][2]);
                    acc[r][3] = fmaf(xs, wv0.w, acc[r][3]);
                    acc[r][4] = fmaf(xs, wv1.x, acc[r][4]);
                    acc[r][5] = fmaf(xs, wv1.y, acc[r][5]);
                    acc[r][6] = fmaf(xs, wv1.z, acc[r][6]);
                    acc[r][7] = fmaf(xs, wv1.w, acc[r][7]);
                }
            }
        }
    };

    // ---- Q = x@Wq + bq -> sQ ----
    proj(Wq, bq);
    #pragma unroll
    for (int r = 0; r < R; ++r) {
        sQ4[(w0 + r) * P4 + tn * 2]     = make_float4(acc[r][0], acc[r][1], acc[r][2], acc[r][3]);
        sQ4[(w0 + r) * P4 + tn * 2 + 1] = make_float4(acc[r][4], acc[r][5], acc[r][6], acc[r][7]);
    }
    // ---- K = x@Wk + bk -> overwrite x region (after all x reads complete) ----
    proj(Wk, bk);
    __syncthreads();
    #pragma unroll
    for (int r = 0; r < R; ++r) {
        sX4[(w0 + r) * P4 + tn * 2]     = make_float4(acc[r][0], acc[r][1], acc[r][2], acc[r][3]);
        sX4[(w0 + r) * P4 + tn * 2 + 1] = make_float4(acc[r][4], acc[r][5], acc[r][6], acc[r][7]);
    }
    __syncthreads();

    // ---- per-head scores + softmax + abar ----
    const int ti  = tid / GRP;
    const int tj  = tid & (GRP - 1);
    const int wid = tid >> 6;
    const bool act = (L != 8) || (ti < 8);   // wave-uniform for L==8

    for (int h = 0; h < NH; ++h) {
        float pm[CPT];
        #pragma unroll
        for (int c = 0; c < CPT; ++c) pm[c] = 0.f;
        if (act) {
            float sc[RPT][CPT];
            #pragma unroll
            for (int r = 0; r < RPT; ++r)
                #pragma unroll
                for (int c = 0; c < CPT; ++c) sc[r][c] = 0.f;
            for (int dq = 0; dq < 16; ++dq) {
                const int du = h * 16 + dq;
                float4 kv[CPT];
                #pragma unroll
                for (int c = 0; c < CPT; ++c) kv[c] = sX4[(tj + 8 * c) * P4 + du];
                #pragma unroll
                for (int r = 0; r < RPT; ++r) {
                    const float4 qv = sQ4[(ti + 32 * r) * P4 + du];
                    #pragma unroll
                    for (int c = 0; c < CPT; ++c)
                        sc[r][c] += qv.x * kv[c].x + qv.y * kv[c].y
                                  + qv.z * kv[c].z + qv.w * kv[c].w;
                }
            }
            #pragma unroll
            for (int r = 0; r < RPT; ++r) {
                const int irow = ti + 32 * r;
                float mx = -3.4e38f;
                #pragma unroll
                for (int c = 0; c < CPT; ++c) {
                    const int j = tj + 8 * c;
                    float s = sc[r][c] * 0.125f;
                    if (sM[j] <= 0.f) s = -1e9f;
                    sc[r][c] = s;
                    mx = fmaxf(mx, s);
                }
                #pragma unroll
                for (int o = 1; o < GRP; o <<= 1) mx = fmaxf(mx, __shfl_xor(mx, o));
                float e[CPT], se = 0.f;
                #pragma unroll
                for (int c = 0; c < CPT; ++c) { e[c] = expf(sc[r][c] - mx); se += e[c]; }
                #pragma unroll
                for (int o = 1; o < GRP; o <<= 1) se += __shfl_xor(se, o);
                const float wr = sM[irow] / se;   // m_i * (1/rowsum)
                #pragma unroll
                for (int c = 0; c < CPT; ++c) pm[c] += e[c] * wr;
            }
        }
        #pragma unroll
        for (int o = GRP; o < 64; o <<= 1)
            #pragma unroll
            for (int c = 0; c < CPT; ++c) pm[c] += __shfl_xor(pm[c], o);
        if ((tid & 63) < GRP) {
            #pragma unroll
            for (int c = 0; c < CPT; ++c) sPart[wid][tj + 8 * c] = pm[c];
        }
        __syncthreads();
        if (tid < L)
            sAbar[h][tid] = sPart[0][tid] + sPart[1][tid] + sPart[2][tid] + sPart[3][tid];
        __syncthreads();
    }

    // ---- z_h = abar_h @ x  (x re-read from global; LDS copy holds K now) ----
    float zz[NH] = {0.f, 0.f, 0.f, 0.f};
    for (int w = 0; w < L; ++w) {
        const float xw = Xs[(size_t)w * D + tid];
        #pragma unroll
        for (int h = 0; h < NH; ++h) zz[h] = fmaf(sAbar[h][w], xw, zz[h]);
    }
    #pragma unroll
    for (int h = 0; h < NH; ++h) sZ[h][tid] = zz[h];
    __syncthreads();

    // ---- pp = z @ Wv + cnt*bv ----
    {
        const int h = tid >> 6;
        float a = sCnt * bv[tid];
        #pragma unroll 8
        for (int d = 0; d < D; ++d) a = fmaf(sZ[h][d], Wv[d * D + tid], a);
        sPP[tid] = a;
    }
    __syncthreads();

    // ---- Out = (pp @ Wo)/cnt + bo  (exact 0 if cnt==0) ----
    {
        float a = 0.f;
        #pragma unroll 8
        for (int d = 0; d < D; ++d) a = fmaf(sPP[d], Wo[d * D + tid], a);
        const float cnt = sCnt;
        Out[(size_t)seq * D + tid] = (cnt > 0.f) ? (a / cnt + bo[tid]) : 0.f;
        if (MaskOut && tid == 0) MaskOut[seq] = (cnt > 0.f) ? 1.f : 0.f;
    }
}

extern "C" void kernel_launch(void* const* d_in, const int* in_sizes, int n_in,
                              void* d_out, int out_size, void* d_ws, size_t ws_size,
                              hipStream_t stream)
{
    const float* emb  = (const float*)d_in[0];
    const int*  amask = (const int*)d_in[1];
    const float* W[24];
    for (int i = 0; i < 24; ++i) W[i] = (const float*)d_in[2 + i];
    // W[0..7]  = wWq,wWk,wWv,wWo,wbq,wbk,wbv,wbo
    // W[8..15] = sWq..sbo ; W[16..23] = cWq..cbo

    float* ws    = (float*)d_ws;
    float* sent  = ws;                   // 2048*256
    float* smask = sent + 2048 * 256;    // 2048
    float* sec   = smask + 2048;         // 128*256
    float* cmask = sec + 128 * 256;      // 128
    float* out   = (float*)d_out;        // 16*256

    // word level: 2048 sequences of 64 tokens
    mha_pool_kernel<64, int><<<dim3(2048), dim3(256), 0, stream>>>(
        emb, amask, W[0], W[1], W[2], W[3], W[4], W[5], W[6], W[7], sent, smask);
    // sentence level: 128 sequences of 16
    mha_pool_kernel<16, float><<<dim3(128), dim3(256), 0, stream>>>(
        sent, smask, W[8], W[9], W[10], W[11], W[12], W[13], W[14], W[15], sec, cmask);
    // section level: 16 sequences of 8
    mha_pool_kernel<8, float><<<dim3(16), dim3(256), 0, stream>>>(
        sec, cmask, W[16], W[17], W[18], W[19], W[20], W[21], W[22], W[23], out, nullptr);
}

// Round 2
// 265.429 us; speedup vs baseline: 3.3461x; 3.3461x over previous
//
#include <hip/hip_runtime.h>

constexpr int D  = 256;
constexpr int NH = 4;

typedef __attribute__((ext_vector_type(8))) __bf16 bf16x8;
typedef __attribute__((ext_vector_type(4))) float f32x4;

__device__ inline unsigned short f2b(float f) {
    unsigned u = __builtin_bit_cast(unsigned, f);
    u = (u + 0x7fffu + ((u >> 16) & 1u)) >> 16;   // RNE
    return (unsigned short)u;
}
__device__ inline bf16x8 ld_frag(const void* p) {
    uint4 r = *(const uint4*)p;
    return __builtin_bit_cast(bf16x8, r);
}

// ---- prep: WT[c][k] = bf16( c<256 ? Wq[k][c] : Wk[k][c-256] ), [512][256] ----
__global__ void prep_wt(const float* __restrict__ Wq, const float* __restrict__ Wk,
                        unsigned short* __restrict__ WT) {
    const int c = blockIdx.x, k = threadIdx.x;
    const float* W = (c < 256) ? Wq : Wk;
    WT[c * 256 + k] = f2b(W[k * 256 + (c & 255)]);
}

// ======================= word level: L=64, MFMA bf16 QK path =======================
// block = 512 threads = 8 waves, one block per sequence.
__global__ __launch_bounds__(512, 4)
void word_kernel(const float* __restrict__ X, const int* __restrict__ Mask,
                 const unsigned short* __restrict__ WT,
                 const float* __restrict__ bq, const float* __restrict__ bk,
                 const float* __restrict__ Wv, const float* __restrict__ Wo,
                 const float* __restrict__ bv, const float* __restrict__ bo,
                 float* __restrict__ Out, float* __restrict__ MaskOut)
{
    __shared__ unsigned short sQK[64 * 512];  // 64KB; first 32KB doubles as bf16 X during proj
    __shared__ float sM[64];
    __shared__ float sPart[8][64];
    __shared__ float sAbar[NH][64];
    __shared__ float sZ[NH][D];
    __shared__ float sPPh[2][D];
    __shared__ float sOuth[2][D];
    __shared__ float sCnt;

    const int tid = threadIdx.x;
    const int seq = blockIdx.x;
    const float* Xs = X + (size_t)seq * 64 * D;
    char* sB = (char*)sQK;

    // ---- stage X -> bf16 LDS (pitch 512B, XOR-swizzled granules) ----
    {
        const float4* X4 = (const float4*)Xs;
        #pragma unroll
        for (int j = 0; j < 8; ++j) {
            int i = tid + j * 512;
            int row = i >> 6, c4 = i & 63;
            float4 v = X4[i];
            uint2 pk;
            pk.x = (unsigned)f2b(v.x) | ((unsigned)f2b(v.y) << 16);
            pk.y = (unsigned)f2b(v.z) | ((unsigned)f2b(v.w) << 16);
            int addr = row * 512 + ((c4 * 8) ^ ((row & 7) << 4));
            *(uint2*)(sB + addr) = pk;
        }
        if (tid < 64) sM[tid] = (float)Mask[seq * 64 + tid];
    }
    __syncthreads();
    if (tid == 0) { float c = 0.f; for (int w = 0; w < 64; ++w) c += sM[w]; sCnt = c; }

    const int lane = tid & 63, w = tid >> 6;
    const int lr = lane & 15, lg = lane >> 4;

    // ---- proj: [Q|K](64x512) = X(64x256) @ [Wq|Wk]; wave w -> cols [w*64, w*64+64) ----
    f32x4 acc[4][4];
    {
        const float* bias = (w < 4) ? bq : bk;
        const int cbase = (w & 3) * 64;
        #pragma unroll
        for (int n = 0; n < 4; ++n) {
            float b = bias[cbase + n * 16 + lr];
            #pragma unroll
            for (int m = 0; m < 4; ++m) acc[m][n] = (f32x4){b, b, b, b};
        }
        #pragma unroll 1
        for (int kk = 0; kk < 8; ++kk) {
            bf16x8 af[4];
            #pragma unroll
            for (int m = 0; m < 4; ++m) {
                int row = m * 16 + lr;
                af[m] = ld_frag(sB + row * 512 + ((kk * 64 + lg * 16) ^ ((row & 7) << 4)));
            }
            #pragma unroll
            for (int n = 0; n < 4; ++n) {
                int c = w * 64 + n * 16 + lr;
                bf16x8 bfr = ld_frag(WT + c * 256 + kk * 32 + lg * 8);
                #pragma unroll
                for (int m = 0; m < 4; ++m)
                    acc[m][n] = __builtin_amdgcn_mfma_f32_16x16x32_bf16(af[m], bfr, acc[m][n], 0, 0, 0);
            }
        }
    }
    __syncthreads();   // all X reads done before overwrite
    // ---- write Q|K bf16 into sQK[64][512] (pitch 1024B, swizzled); C layout: col=lr, row=lg*4+r ----
    #pragma unroll
    for (int m = 0; m < 4; ++m)
        #pragma unroll
        for (int n = 0; n < 4; ++n) {
            int col = w * 64 + n * 16 + lr;
            #pragma unroll
            for (int r = 0; r < 4; ++r) {
                int row = m * 16 + lg * 4 + r;
                *(unsigned short*)(sB + row * 1024 + ((col * 2) ^ ((row & 7) << 4))) = f2b(acc[m][n][r]);
            }
        }
    __syncthreads();

    // ---- scores + softmax + abar; wave pair per head: h=w>>1, rows msel*32..+31 ----
    {
        const int h = w >> 1, msel = w & 1;
        f32x4 sacc[2][4];
        #pragma unroll
        for (int m = 0; m < 2; ++m)
            #pragma unroll
            for (int n = 0; n < 4; ++n) sacc[m][n] = (f32x4){0.f, 0.f, 0.f, 0.f};
        #pragma unroll
        for (int kk = 0; kk < 2; ++kk) {
            bf16x8 qf[2];
            #pragma unroll
            for (int m = 0; m < 2; ++m) {
                int row = msel * 32 + m * 16 + lr;
                qf[m] = ld_frag(sB + row * 1024 + ((h * 128 + kk * 64 + lg * 16) ^ ((row & 7) << 4)));
            }
            #pragma unroll
            for (int n = 0; n < 4; ++n) {
                int row = n * 16 + lr;
                bf16x8 kf = ld_frag(sB + row * 1024 + ((512 + h * 128 + kk * 64 + lg * 16) ^ ((row & 7) << 4)));
                #pragma unroll
                for (int m = 0; m < 2; ++m)
                    sacc[m][n] = __builtin_amdgcn_mfma_f32_16x16x32_bf16(qf[m], kf, sacc[m][n], 0, 0, 0);
            }
        }
        float mcol[4];
        #pragma unroll
        for (int n = 0; n < 4; ++n) mcol[n] = sM[n * 16 + lr];
        float pm[4] = {0.f, 0.f, 0.f, 0.f};
        #pragma unroll
        for (int m = 0; m < 2; ++m)
            #pragma unroll
            for (int r = 0; r < 4; ++r) {
                float s[4], mx = -3.4e38f;
                #pragma unroll
                for (int n = 0; n < 4; ++n) {
                    float v = sacc[m][n][r] * 0.125f;
                    if (mcol[n] <= 0.f) v = -1e9f;
                    s[n] = v; mx = fmaxf(mx, v);
                }
                #pragma unroll
                for (int o = 1; o < 16; o <<= 1) mx = fmaxf(mx, __shfl_xor(mx, o));
                float e[4], se = 0.f;
                #pragma unroll
                for (int n = 0; n < 4; ++n) { e[n] = expf(s[n] - mx); se += e[n]; }
                #pragma unroll
                for (int o = 1; o < 16; o <<= 1) se += __shfl_xor(se, o);
                const int rowtok = msel * 32 + m * 16 + lg * 4 + r;
                const float wr = sM[rowtok] / se;    // m_row * (1/rowsum)
                #pragma unroll
                for (int n = 0; n < 4; ++n) pm[n] += e[n] * wr;
            }
        #pragma unroll
        for (int o = 16; o < 64; o <<= 1)
            #pragma unroll
            for (int n = 0; n < 4; ++n) pm[n] += __shfl_xor(pm[n], o);
        if (lane < 16)
            #pragma unroll
            for (int n = 0; n < 4; ++n) sPart[w][n * 16 + lane] = pm[n];
    }
    __syncthreads();
    if (tid < 256) {
        int h = tid >> 6, j = tid & 63;
        sAbar[h][j] = sPart[2 * h][j] + sPart[2 * h + 1][j];
    }
    __syncthreads();

    // ---- z_h = abar_h @ X (fp32 X from global; L3-resident 2nd read) ----
    {
        int d = tid & 255, hp = (tid >> 8) * 2;
        float z0 = 0.f, z1 = 0.f;
        #pragma unroll 8
        for (int ww = 0; ww < 64; ++ww) {
            float xv = Xs[ww * 256 + d];
            z0 = fmaf(sAbar[hp][ww], xv, z0);
            z1 = fmaf(sAbar[hp + 1][ww], xv, z1);
        }
        sZ[hp][d] = z0; sZ[hp + 1][d] = z1;
    }
    __syncthreads();
    // ---- pp = z@Wv + cnt*bv (split-K over 2 halves) ----
    {
        int n = tid & 255, half = tid >> 8, h = n >> 6;
        float a = half ? 0.f : sCnt * bv[n];
        const float* wvp = Wv + half * 128 * 256 + n;
        const float* zp  = sZ[h] + half * 128;
        #pragma unroll 8
        for (int d = 0; d < 128; ++d) a = fmaf(zp[d], wvp[d * 256], a);
        sPPh[half][n] = a;
    }
    __syncthreads();
    if (tid < 256) sPPh[0][tid] += sPPh[1][tid];
    __syncthreads();
    // ---- out = (pp@Wo)/cnt + bo ----
    {
        int n = tid & 255, half = tid >> 8;
        float a = 0.f;
        const float* wop = Wo + half * 128 * 256 + n;
        const float* pp  = sPPh[0] + half * 128;
        #pragma unroll 8
        for (int d = 0; d < 128; ++d) a = fmaf(pp[d], wop[d * 256], a);
        sOuth[half][n] = a;
    }
    __syncthreads();
    if (tid < 256) {
        float cnt = sCnt;
        Out[(size_t)seq * D + tid] = (cnt > 0.f) ? ((sOuth[0][tid] + sOuth[1][tid]) / cnt + bo[tid]) : 0.f;
        if (MaskOut && tid == 0) MaskOut[seq] = (cnt > 0.f) ? 1.f : 0.f;
    }
}

// ======================= levels 2/3: fp32 template (unchanged from R1) =======================
template<int L, typename MT>
__global__ __launch_bounds__(256, 1)
void mha_pool_kernel(const float* __restrict__ X,
                     const MT* __restrict__ Mask,
                     const float* __restrict__ Wq, const float* __restrict__ Wk,
                     const float* __restrict__ Wv, const float* __restrict__ Wo,
                     const float* __restrict__ bq, const float* __restrict__ bk,
                     const float* __restrict__ bv, const float* __restrict__ bo,
                     float* __restrict__ Out, float* __restrict__ MaskOut)
{
    constexpr int R   = L / 8;
    constexpr int P4  = 65;
    constexpr int GRP = (L == 16) ? 16 : 8;
    constexpr int CPT = (L == 64) ? 8 : 1;
    constexpr int RPT = (L == 64) ? 2 : 1;

    __shared__ float sX[L * P4 * 4];
    __shared__ float sQ[L * P4 * 4];
    __shared__ float sZ[NH][D];
    __shared__ float sAbar[NH][64];
    __shared__ float sPart[4][64];
    __shared__ float sM[64];
    __shared__ float sPP[D];
    __shared__ float sCnt;

    const int tid = threadIdx.x;
    const int seq = blockIdx.x;
    const float* Xs = X + (size_t)seq * L * D;

    float4* sX4 = (float4*)sX;
    float4* sQ4 = (float4*)sQ;
    const float4* X4 = (const float4*)Xs;

    if (tid < L) sM[tid] = (float)Mask[(size_t)seq * L + tid];
    for (int i = tid; i < L * 64; i += 256) {
        const int row = i >> 6, c4 = i & 63;
        sX4[row * P4 + c4] = X4[i];
    }
    __syncthreads();
    if (tid == 0) {
        float c = 0.f;
        for (int w = 0; w < L; ++w) c += sM[w];
        sCnt = c;
    }

    const int tn = tid & 31, tw = tid >> 5;
    const int n0 = tn * 8, w0 = tw * R;

    float acc[R][8];

    auto proj = [&](const float* __restrict__ W, const float* __restrict__ bias) {
        const float4* Wg4 = (const float4*)W;
        #pragma unroll
        for (int r = 0; r < R; ++r)
            #pragma unroll
            for (int c = 0; c < 8; ++c) acc[r][c] = bias[n0 + c];
        #pragma unroll 2
        for (int dq = 0; dq < 64; ++dq) {
            float4 xv[R];
            #pragma unroll
            for (int r = 0; r < R; ++r) xv[r] = sX4[(w0 + r) * P4 + dq];
            #pragma unroll
            for (int e = 0; e < 4; ++e) {
                const int d = dq * 4 + e;
                const float4 wv0 = Wg4[d * 64 + tn * 2];
                const float4 wv1 = Wg4[d * 64 + tn * 2 + 1];
                #pragma unroll
                for (int r = 0; r < R; ++r) {
                    const float xs = (e == 0) ? xv[r].x : (e == 1) ? xv[r].y
                                   : (e == 2) ? xv[r].z : xv[r].w;
                    acc[r][0] = fmaf(xs, wv0.x, acc[r][0]);
                    acc[r][1] = fmaf(xs, wv0.y, acc[r][1]);
                    acc[r][2] = fmaf(xs, wv0.z, acc[r][2]);
                    acc[r][3] = fmaf(xs, wv0.w, acc[r][3]);
                    acc[r][4] = fmaf(xs, wv1.x, acc[r][4]);
                    acc[r][5] = fmaf(xs, wv1.y, acc[r][5]);
                    acc[r][6] = fmaf(xs, wv1.z, acc[r][6]);
                    acc[r][7] = fmaf(xs, wv1.w, acc[r][7]);
                }
            }
        }
    };

    proj(Wq, bq);
    #pragma unroll
    for (int r = 0; r < R; ++r) {
        sQ4[(w0 + r) * P4 + tn * 2]     = make_float4(acc[r][0], acc[r][1], acc[r][2], acc[r][3]);
        sQ4[(w0 + r) * P4 + tn * 2 + 1] = make_float4(acc[r][4], acc[r][5], acc[r][6], acc[r][7]);
    }
    proj(Wk, bk);
    __syncthreads();
    #pragma unroll
    for (int r = 0; r < R; ++r) {
        sX4[(w0 + r) * P4 + tn * 2]     = make_float4(acc[r][0], acc[r][1], acc[r][2], acc[r][3]);
        sX4[(w0 + r) * P4 + tn * 2 + 1] = make_float4(acc[r][4], acc[r][5], acc[r][6], acc[r][7]);
    }
    __syncthreads();

    const int ti  = tid / GRP;
    const int tj  = tid & (GRP - 1);
    const int wid = tid >> 6;
    const bool act = (L != 8) || (ti < 8);

    for (int h = 0; h < NH; ++h) {
        float pm[CPT];
        #pragma unroll
        for (int c = 0; c < CPT; ++c) pm[c] = 0.f;
        if (act) {
            float sc[RPT][CPT];
            #pragma unroll
            for (int r = 0; r < RPT; ++r)
                #pragma unroll
                for (int c = 0; c < CPT; ++c) sc[r][c] = 0.f;
            for (int dq = 0; dq < 16; ++dq) {
                const int du = h * 16 + dq;
                float4 kv[CPT];
                #pragma unroll
                for (int c = 0; c < CPT; ++c) kv[c] = sX4[(tj + 8 * c) * P4 + du];
                #pragma unroll
                for (int r = 0; r < RPT; ++r) {
                    const float4 qv = sQ4[(ti + 32 * r) * P4 + du];
                    #pragma unroll
                    for (int c = 0; c < CPT; ++c)
                        sc[r][c] += qv.x * kv[c].x + qv.y * kv[c].y
                                  + qv.z * kv[c].z + qv.w * kv[c].w;
                }
            }
            #pragma unroll
            for (int r = 0; r < RPT; ++r) {
                const int irow = ti + 32 * r;
                float mx = -3.4e38f;
                #pragma unroll
                for (int c = 0; c < CPT; ++c) {
                    const int j = tj + 8 * c;
                    float s = sc[r][c] * 0.125f;
                    if (sM[j] <= 0.f) s = -1e9f;
                    sc[r][c] = s;
                    mx = fmaxf(mx, s);
                }
                #pragma unroll
                for (int o = 1; o < GRP; o <<= 1) mx = fmaxf(mx, __shfl_xor(mx, o));
                float e[CPT], se = 0.f;
                #pragma unroll
                for (int c = 0; c < CPT; ++c) { e[c] = expf(sc[r][c] - mx); se += e[c]; }
                #pragma unroll
                for (int o = 1; o < GRP; o <<= 1) se += __shfl_xor(se, o);
                const float wr = sM[irow] / se;
                #pragma unroll
                for (int c = 0; c < CPT; ++c) pm[c] += e[c] * wr;
            }
        }
        #pragma unroll
        for (int o = GRP; o < 64; o <<= 1)
            #pragma unroll
            for (int c = 0; c < CPT; ++c) pm[c] += __shfl_xor(pm[c], o);
        if ((tid & 63) < GRP) {
            #pragma unroll
            for (int c = 0; c < CPT; ++c) sPart[wid][tj + 8 * c] = pm[c];
        }
        __syncthreads();
        if (tid < L)
            sAbar[h][tid] = sPart[0][tid] + sPart[1][tid] + sPart[2][tid] + sPart[3][tid];
        __syncthreads();
    }

    float zz[NH] = {0.f, 0.f, 0.f, 0.f};
    for (int w = 0; w < L; ++w) {
        const float xw = Xs[(size_t)w * D + tid];
        #pragma unroll
        for (int h = 0; h < NH; ++h) zz[h] = fmaf(sAbar[h][w], xw, zz[h]);
    }
    #pragma unroll
    for (int h = 0; h < NH; ++h) sZ[h][tid] = zz[h];
    __syncthreads();

    {
        const int h = tid >> 6;
        float a = sCnt * bv[tid];
        #pragma unroll 8
        for (int d = 0; d < D; ++d) a = fmaf(sZ[h][d], Wv[d * D + tid], a);
        sPP[tid] = a;
    }
    __syncthreads();

    {
        float a = 0.f;
        #pragma unroll 8
        for (int d = 0; d < D; ++d) a = fmaf(sPP[d], Wo[d * D + tid], a);
        const float cnt = sCnt;
        Out[(size_t)seq * D + tid] = (cnt > 0.f) ? (a / cnt + bo[tid]) : 0.f;
        if (MaskOut && tid == 0) MaskOut[seq] = (cnt > 0.f) ? 1.f : 0.f;
    }
}

extern "C" void kernel_launch(void* const* d_in, const int* in_sizes, int n_in,
                              void* d_out, int out_size, void* d_ws, size_t ws_size,
                              hipStream_t stream)
{
    const float* emb  = (const float*)d_in[0];
    const int*  amask = (const int*)d_in[1];
    const float* W[24];
    for (int i = 0; i < 24; ++i) W[i] = (const float*)d_in[2 + i];

    char* ws = (char*)d_ws;
    unsigned short* WT = (unsigned short*)ws;              // 512*256*2 = 256KB
    float* sent  = (float*)(ws + 256 * 1024);              // 2048*256
    float* smask = sent + 2048 * 256;                      // 2048
    float* sec   = smask + 2048;                           // 128*256
    float* cmask = sec + 128 * 256;                        // 128
    float* out   = (float*)d_out;                          // 16*256

    prep_wt<<<dim3(512), dim3(256), 0, stream>>>(W[0], W[1], WT);

    word_kernel<<<dim3(2048), dim3(512), 0, stream>>>(
        emb, amask, WT, W[4], W[5], W[2], W[3], W[6], W[7], sent, smask);

    mha_pool_kernel<16, float><<<dim3(128), dim3(256), 0, stream>>>(
        sent, smask, W[8], W[9], W[10], W[11], W[12], W[13], W[14], W[15], sec, cmask);
    mha_pool_kernel<8, float><<<dim3(16), dim3(256), 0, stream>>>(
        sec, cmask, W[16], W[17], W[18], W[19], W[20], W[21], W[22], W[23], out, nullptr);
}

// Round 3
// 250.212 us; speedup vs baseline: 3.5495x; 1.0608x over previous
//
#include <hip/hip_runtime.h>

constexpr int D  = 256;
constexpr int NH = 4;

typedef __attribute__((ext_vector_type(8))) __bf16 bf16x8;
typedef __attribute__((ext_vector_type(4))) float f32x4;

__device__ inline unsigned short f2b(float f) {
    unsigned u = __builtin_bit_cast(unsigned, f);
    u = (u + 0x7fffu + ((u >> 16) & 1u)) >> 16;   // RNE
    return (unsigned short)u;
}
__device__ inline unsigned cvt_pk_bf16(float lo, float hi) {
    unsigned r;
    asm volatile("v_cvt_pk_bf16_f32 %0, %1, %2" : "=v"(r) : "v"(lo), "v"(hi));
    return r;
}
__device__ inline bf16x8 ld_frag(const void* p) {
    uint4 r = *(const uint4*)p;
    return __builtin_bit_cast(bf16x8, r);
}

// ---- prep: WT[c][k] = bf16( c<256 ? Wq[k][c] : Wk[k][c-256] ), [512][256] ----
__global__ void prep_wt(const float* __restrict__ Wq, const float* __restrict__ Wk,
                        unsigned short* __restrict__ WT) {
    const int c = blockIdx.x, k = threadIdx.x;
    const float* W = (c < 256) ? Wq : Wk;
    WT[c * 256 + k] = f2b(W[k * 256 + (c & 255)]);
}

// =============== K1: word attention -> abar[seq][4][64], cnt[seq] ===============
// proj computes Q^T/K^T = WT @ X^T so the C-fragment is token-per-lane with 4
// consecutive features per lane -> vector ds_write_b64 writeback (no transpose).
__global__ __launch_bounds__(512, 4)
void word_attn_kernel(const float* __restrict__ X, const int* __restrict__ Mask,
                      const unsigned short* __restrict__ WT,
                      const float* __restrict__ bq, const float* __restrict__ bk,
                      float* __restrict__ Abar, float* __restrict__ Cnt)
{
    __shared__ unsigned short sQK[64 * 512];  // 64KB; X bf16 [64][256] lives in first 32KB during proj
    __shared__ float sM[64];
    __shared__ float sPart[8][64];
    __shared__ float sCnt;

    const int tid = threadIdx.x;
    const int seq = blockIdx.x;
    const float* Xs = X + (size_t)seq * 64 * D;
    char* sB = (char*)sQK;

    // ---- stage X -> bf16 LDS [64][256], pitch 512B, swizzle ((row&7)<<4) ----
    {
        const float4* X4 = (const float4*)Xs;
        #pragma unroll
        for (int j = 0; j < 8; ++j) {
            int i = tid + j * 512;
            int row = i >> 6, c4 = i & 63;
            float4 v = X4[i];
            uint2 pk;
            pk.x = (unsigned)f2b(v.x) | ((unsigned)f2b(v.y) << 16);
            pk.y = (unsigned)f2b(v.z) | ((unsigned)f2b(v.w) << 16);
            int addr = row * 512 + ((c4 * 8) ^ ((row & 7) << 4));
            *(uint2*)(sB + addr) = pk;
        }
        if (tid < 64) sM[tid] = (float)Mask[seq * 64 + tid];
    }
    __syncthreads();
    if (tid == 0) { float c = 0.f; for (int t = 0; t < 64; ++t) c += sM[t]; sCnt = c; }

    const int lane = tid & 63, w = tid >> 6;
    const int lr = lane & 15, lg = lane >> 4;

    // ---- proj': C[feature][token]; wave w owns features w*64..+63 (Q: w<4, K: w>=4) ----
    f32x4 acc[4][4];
    {
        const float* bias = (w < 4) ? bq : bk;
        const int fb = (w & 3) * 64;
        #pragma unroll
        for (int m = 0; m < 4; ++m) {
            float4 b4 = *(const float4*)(bias + fb + m * 16 + lg * 4);
            f32x4 bi = {b4.x, b4.y, b4.z, b4.w};
            #pragma unroll
            for (int n = 0; n < 4; ++n) acc[m][n] = bi;
        }
        #pragma unroll 1
        for (int kk = 0; kk < 8; ++kk) {
            bf16x8 bx[4];                       // B-frag: col = token n*16+lr, 8 k's
            #pragma unroll
            for (int n = 0; n < 4; ++n) {
                int t = n * 16 + lr;
                bx[n] = ld_frag(sB + t * 512 + ((kk * 64 + lg * 16) ^ ((t & 7) << 4)));
            }
            #pragma unroll
            for (int m = 0; m < 4; ++m) {
                int f = w * 64 + m * 16 + lr;   // A-frag: row = feature, 8 k's
                bf16x8 af = ld_frag(WT + f * 256 + kk * 32 + lg * 8);
                #pragma unroll
                for (int n = 0; n < 4; ++n)
                    acc[m][n] = __builtin_amdgcn_mfma_f32_16x16x32_bf16(af, bx[n], acc[m][n], 0, 0, 0);
            }
        }
    }
    __syncthreads();   // all X reads done before overwrite
    // ---- writeback token-major Q|K bf16 [64][512], pitch 1024B, swizzled ----
    #pragma unroll
    for (int n = 0; n < 4; ++n) {
        int t = n * 16 + lr;
        char* rowp = sB + t * 1024;
        int sw = (t & 7) << 4;
        #pragma unroll
        for (int m = 0; m < 4; ++m) {
            uint2 pk;
            pk.x = cvt_pk_bf16(acc[m][n][0], acc[m][n][1]);
            pk.y = cvt_pk_bf16(acc[m][n][2], acc[m][n][3]);
            *(uint2*)(rowp + ((w * 128 + m * 32 + lg * 8) ^ sw)) = pk;
        }
    }
    __syncthreads();

    // ---- scores + softmax + abar; h = w>>1, query rows msel*32..+31 ----
    {
        const int h = w >> 1, msel = w & 1;
        f32x4 sacc[2][4];
        #pragma unroll
        for (int m = 0; m < 2; ++m)
            #pragma unroll
            for (int n = 0; n < 4; ++n) sacc[m][n] = (f32x4){0.f, 0.f, 0.f, 0.f};
        #pragma unroll
        for (int kk = 0; kk < 2; ++kk) {
            bf16x8 qf[2];
            #pragma unroll
            for (int m = 0; m < 2; ++m) {
                int t = msel * 32 + m * 16 + lr;
                qf[m] = ld_frag(sB + t * 1024 + ((h * 128 + kk * 64 + lg * 16) ^ ((t & 7) << 4)));
            }
            #pragma unroll
            for (int n = 0; n < 4; ++n) {
                int t = n * 16 + lr;
                bf16x8 kf = ld_frag(sB + t * 1024 + ((512 + h * 128 + kk * 64 + lg * 16) ^ ((t & 7) << 4)));
                #pragma unroll
                for (int m = 0; m < 2; ++m)
                    sacc[m][n] = __builtin_amdgcn_mfma_f32_16x16x32_bf16(qf[m], kf, sacc[m][n], 0, 0, 0);
            }
        }
        float mcol[4];
        #pragma unroll
        for (int n = 0; n < 4; ++n) mcol[n] = sM[n * 16 + lr];
        constexpr float CE = 0.125f * 1.44269504f;   // fold 1/sqrt(dh) into exp2
        float pm[4] = {0.f, 0.f, 0.f, 0.f};
        #pragma unroll
        for (int m = 0; m < 2; ++m)
            #pragma unroll
            for (int r = 0; r < 4; ++r) {
                float s[4], mx = -3.4e38f;
                #pragma unroll
                for (int n = 0; n < 4; ++n) {
                    float v = sacc[m][n][r];
                    if (mcol[n] <= 0.f) v = -1e9f;
                    s[n] = v; mx = fmaxf(mx, v);
                }
                #pragma unroll
                for (int o = 1; o < 16; o <<= 1) mx = fmaxf(mx, __shfl_xor(mx, o));
                float e[4], se = 0.f;
                #pragma unroll
                for (int n = 0; n < 4; ++n) { e[n] = exp2f((s[n] - mx) * CE); se += e[n]; }
                #pragma unroll
                for (int o = 1; o < 16; o <<= 1) se += __shfl_xor(se, o);
                const int rowtok = msel * 32 + m * 16 + lg * 4 + r;
                const float wr = sM[rowtok] / se;
                #pragma unroll
                for (int n = 0; n < 4; ++n) pm[n] += e[n] * wr;
            }
        #pragma unroll
        for (int o = 16; o < 64; o <<= 1)
            #pragma unroll
            for (int n = 0; n < 4; ++n) pm[n] += __shfl_xor(pm[n], o);
        if (lane < 16)
            #pragma unroll
            for (int n = 0; n < 4; ++n) sPart[w][n * 16 + lane] = pm[n];
    }
    __syncthreads();
    if (tid < 256) {
        int h = tid >> 6, j = tid & 63;
        Abar[(size_t)seq * 256 + tid] = sPart[2 * h][j] + sPart[2 * h + 1][j];
    }
    if (tid == 0) Cnt[seq] = sCnt;
}

// =============== K2: z = abar@X ; pp = z@Wv + cnt*bv ; out = pp@Wo/cnt + bo ===============
// 8 sequences per block: Wv/Wo read once per 8 seqs.
__global__ __launch_bounds__(512, 2)
void word_apply_kernel(const float* __restrict__ X, const float* __restrict__ Abar,
                       const float* __restrict__ Cnt,
                       const float* __restrict__ Wv, const float* __restrict__ Wo,
                       const float* __restrict__ bv, const float* __restrict__ bo,
                       float* __restrict__ Out, float* __restrict__ MaskOut)
{
    constexpr int SPB = 8;
    __shared__ float sAb[SPB][4][64];   // 8KB
    __shared__ float sZ[SPB][4][256];   // 32KB
    __shared__ float sPP[SPB][256];     // 8KB
    __shared__ float sH[2][SPB][256];   // 16KB
    __shared__ float sCt[SPB];

    const int tid = threadIdx.x;
    const int s0 = blockIdx.x * SPB;

    for (int i = tid; i < SPB * 256; i += 512)
        sAb[i >> 8][(i >> 6) & 3][i & 63] = Abar[(size_t)s0 * 256 + i];
    if (tid < SPB) sCt[tid] = Cnt[s0 + tid];
    __syncthreads();

    const int d = tid & 255, rh = tid >> 8;

    // ---- z: tokens split across rh halves, combined through sZ ----
    {
        float zz[SPB][4];
        #pragma unroll
        for (int s = 0; s < SPB; ++s) {
            const float* xp = X + ((size_t)(s0 + s) * 64 + rh * 32) * 256 + d;
            const float* ab0 = &sAb[s][0][rh * 32];
            const float* ab1 = &sAb[s][1][rh * 32];
            const float* ab2 = &sAb[s][2][rh * 32];
            const float* ab3 = &sAb[s][3][rh * 32];
            float a0 = 0.f, a1 = 0.f, a2 = 0.f, a3 = 0.f;
            #pragma unroll 8
            for (int t = 0; t < 32; ++t) {
                float xv = xp[t * 256];
                a0 = fmaf(ab0[t], xv, a0);
                a1 = fmaf(ab1[t], xv, a1);
                a2 = fmaf(ab2[t], xv, a2);
                a3 = fmaf(ab3[t], xv, a3);
            }
            zz[s][0] = a0; zz[s][1] = a1; zz[s][2] = a2; zz[s][3] = a3;
        }
        if (rh == 0) {
            #pragma unroll
            for (int s = 0; s < SPB; ++s)
                #pragma unroll
                for (int h = 0; h < 4; ++h) sZ[s][h][d] = zz[s][h];
        }
        __syncthreads();
        if (rh == 1) {
            #pragma unroll
            for (int s = 0; s < SPB; ++s)
                #pragma unroll
                for (int h = 0; h < 4; ++h) sZ[s][h][d] += zz[s][h];
        }
        __syncthreads();
    }

    const int n = d, g = rh, h = n >> 6;

    // ---- pp = z @ Wv (d-halves split across g) ----
    {
        float pa[SPB];
        #pragma unroll
        for (int s = 0; s < SPB; ++s) pa[s] = 0.f;
        for (int dc = 0; dc < 128; dc += 16) {
            float wv[16];
            #pragma unroll
            for (int q = 0; q < 16; ++q) wv[q] = Wv[(size_t)(g * 128 + dc + q) * 256 + n];
            #pragma unroll
            for (int s = 0; s < SPB; ++s) {
                const float4* zp = (const float4*)&sZ[s][h][g * 128 + dc];
                #pragma unroll
                for (int q4 = 0; q4 < 4; ++q4) {
                    float4 zv = zp[q4];
                    pa[s] = fmaf(zv.x, wv[q4 * 4 + 0], pa[s]);
                    pa[s] = fmaf(zv.y, wv[q4 * 4 + 1], pa[s]);
                    pa[s] = fmaf(zv.z, wv[q4 * 4 + 2], pa[s]);
                    pa[s] = fmaf(zv.w, wv[q4 * 4 + 3], pa[s]);
                }
            }
        }
        #pragma unroll
        for (int s = 0; s < SPB; ++s) sH[g][s][n] = pa[s];
    }
    __syncthreads();
    for (int i = tid; i < SPB * 256; i += 512) {
        int s = i >> 8, nn = i & 255;
        sPP[s][nn] = sH[0][s][nn] + sH[1][s][nn] + sCt[s] * bv[nn];
    }
    __syncthreads();

    // ---- out = pp @ Wo ----
    {
        float pa[SPB];
        #pragma unroll
        for (int s = 0; s < SPB; ++s) pa[s] = 0.f;
        for (int dc = 0; dc < 128; dc += 16) {
            float wo[16];
            #pragma unroll
            for (int q = 0; q < 16; ++q) wo[q] = Wo[(size_t)(g * 128 + dc + q) * 256 + n];
            #pragma unroll
            for (int s = 0; s < SPB; ++s) {
                const float4* pp = (const float4*)&sPP[s][g * 128 + dc];
                #pragma unroll
                for (int q4 = 0; q4 < 4; ++q4) {
                    float4 pv = pp[q4];
                    pa[s] = fmaf(pv.x, wo[q4 * 4 + 0], pa[s]);
                    pa[s] = fmaf(pv.y, wo[q4 * 4 + 1], pa[s]);
                    pa[s] = fmaf(pv.z, wo[q4 * 4 + 2], pa[s]);
                    pa[s] = fmaf(pv.w, wo[q4 * 4 + 3], pa[s]);
                }
            }
        }
        #pragma unroll
        for (int s = 0; s < SPB; ++s) sH[g][s][n] = pa[s];
    }
    __syncthreads();
    for (int i = tid; i < SPB * 256; i += 512) {
        int s = i >> 8, nn = i & 255;
        float c = sCt[s];
        Out[(size_t)(s0 + s) * 256 + nn] = (c > 0.f) ? ((sH[0][s][nn] + sH[1][s][nn]) / c + bo[nn]) : 0.f;
    }
    if (tid < SPB && MaskOut) MaskOut[s0 + tid] = (sCt[tid] > 0.f) ? 1.f : 0.f;
}

// ======================= levels 2/3: fp32 template (unchanged) =======================
template<int L, typename MT>
__global__ __launch_bounds__(256, 1)
void mha_pool_kernel(const float* __restrict__ X,
                     const MT* __restrict__ Mask,
                     const float* __restrict__ Wq, const float* __restrict__ Wk,
                     const float* __restrict__ Wv, const float* __restrict__ Wo,
                     const float* __restrict__ bq, const float* __restrict__ bk,
                     const float* __restrict__ bv, const float* __restrict__ bo,
                     float* __restrict__ Out, float* __restrict__ MaskOut)
{
    constexpr int R   = L / 8;
    constexpr int P4  = 65;
    constexpr int GRP = (L == 16) ? 16 : 8;
    constexpr int CPT = (L == 64) ? 8 : 1;
    constexpr int RPT = (L == 64) ? 2 : 1;

    __shared__ float sX[L * P4 * 4];
    __shared__ float sQ[L * P4 * 4];
    __shared__ float sZ[NH][D];
    __shared__ float sAbar[NH][64];
    __shared__ float sPart[4][64];
    __shared__ float sM[64];
    __shared__ float sPP[D];
    __shared__ float sCnt;

    const int tid = threadIdx.x;
    const int seq = blockIdx.x;
    const float* Xs = X + (size_t)seq * L * D;

    float4* sX4 = (float4*)sX;
    float4* sQ4 = (float4*)sQ;
    const float4* X4 = (const float4*)Xs;

    if (tid < L) sM[tid] = (float)Mask[(size_t)seq * L + tid];
    for (int i = tid; i < L * 64; i += 256) {
        const int row = i >> 6, c4 = i & 63;
        sX4[row * P4 + c4] = X4[i];
    }
    __syncthreads();
    if (tid == 0) {
        float c = 0.f;
        for (int w = 0; w < L; ++w) c += sM[w];
        sCnt = c;
    }

    const int tn = tid & 31, tw = tid >> 5;
    const int n0 = tn * 8, w0 = tw * R;

    float acc[R][8];

    auto proj = [&](const float* __restrict__ W, const float* __restrict__ bias) {
        const float4* Wg4 = (const float4*)W;
        #pragma unroll
        for (int r = 0; r < R; ++r)
            #pragma unroll
            for (int c = 0; c < 8; ++c) acc[r][c] = bias[n0 + c];
        #pragma unroll 2
        for (int dq = 0; dq < 64; ++dq) {
            float4 xv[R];
            #pragma unroll
            for (int r = 0; r < R; ++r) xv[r] = sX4[(w0 + r) * P4 + dq];
            #pragma unroll
            for (int e = 0; e < 4; ++e) {
                const int dd = dq * 4 + e;
                const float4 wv0 = Wg4[dd * 64 + tn * 2];
                const float4 wv1 = Wg4[dd * 64 + tn * 2 + 1];
                #pragma unroll
                for (int r = 0; r < R; ++r) {
                    const float xs = (e == 0) ? xv[r].x : (e == 1) ? xv[r].y
                                   : (e == 2) ? xv[r].z : xv[r].w;
                    acc[r][0] = fmaf(xs, wv0.x, acc[r][0]);
                    acc[r][1] = fmaf(xs, wv0.y, acc[r][1]);
                    acc[r][2] = fmaf(xs, wv0.z, acc[r][2]);
                    acc[r][3] = fmaf(xs, wv0.w, acc[r][3]);
                    acc[r][4] = fmaf(xs, wv1.x, acc[r][4]);
                    acc[r][5] = fmaf(xs, wv1.y, acc[r][5]);
                    acc[r][6] = fmaf(xs, wv1.z, acc[r][6]);
                    acc[r][7] = fmaf(xs, wv1.w, acc[r][7]);
                }
            }
        }
    };

    proj(Wq, bq);
    #pragma unroll
    for (int r = 0; r < R; ++r) {
        sQ4[(w0 + r) * P4 + tn * 2]     = make_float4(acc[r][0], acc[r][1], acc[r][2], acc[r][3]);
        sQ4[(w0 + r) * P4 + tn * 2 + 1] = make_float4(acc[r][4], acc[r][5], acc[r][6], acc[r][7]);
    }
    proj(Wk, bk);
    __syncthreads();
    #pragma unroll
    for (int r = 0; r < R; ++r) {
        sX4[(w0 + r) * P4 + tn * 2]     = make_float4(acc[r][0], acc[r][1], acc[r][2], acc[r][3]);
        sX4[(w0 + r) * P4 + tn * 2 + 1] = make_float4(acc[r][4], acc[r][5], acc[r][6], acc[r][7]);
    }
    __syncthreads();

    const int ti  = tid / GRP;
    const int tj  = tid & (GRP - 1);
    const int wid = tid >> 6;
    const bool act = (L != 8) || (ti < 8);

    for (int h = 0; h < NH; ++h) {
        float pm[CPT];
        #pragma unroll
        for (int c = 0; c < CPT; ++c) pm[c] = 0.f;
        if (act) {
            float sc[RPT][CPT];
            #pragma unroll
            for (int r = 0; r < RPT; ++r)
                #pragma unroll
                for (int c = 0; c < CPT; ++c) sc[r][c] = 0.f;
            for (int dq = 0; dq < 16; ++dq) {
                const int du = h * 16 + dq;
                float4 kv[CPT];
                #pragma unroll
                for (int c = 0; c < CPT; ++c) kv[c] = sX4[(tj + 8 * c) * P4 + du];
                #pragma unroll
                for (int r = 0; r < RPT; ++r) {
                    const float4 qv = sQ4[(ti + 32 * r) * P4 + du];
                    #pragma unroll
                    for (int c = 0; c < CPT; ++c)
                        sc[r][c] += qv.x * kv[c].x + qv.y * kv[c].y
                                  + qv.z * kv[c].z + qv.w * kv[c].w;
                }
            }
            #pragma unroll
            for (int r = 0; r < RPT; ++r) {
                const int irow = ti + 32 * r;
                float mx = -3.4e38f;
                #pragma unroll
                for (int c = 0; c < CPT; ++c) {
                    const int j = tj + 8 * c;
                    float s = sc[r][c] * 0.125f;
                    if (sM[j] <= 0.f) s = -1e9f;
                    sc[r][c] = s;
                    mx = fmaxf(mx, s);
                }
                #pragma unroll
                for (int o = 1; o < GRP; o <<= 1) mx = fmaxf(mx, __shfl_xor(mx, o));
                float e[CPT], se = 0.f;
                #pragma unroll
                for (int c = 0; c < CPT; ++c) { e[c] = expf(sc[r][c] - mx); se += e[c]; }
                #pragma unroll
                for (int o = 1; o < GRP; o <<= 1) se += __shfl_xor(se, o);
                const float wr = sM[irow] / se;
                #pragma unroll
                for (int c = 0; c < CPT; ++c) pm[c] += e[c] * wr;
            }
        }
        #pragma unroll
        for (int o = GRP; o < 64; o <<= 1)
            #pragma unroll
            for (int c = 0; c < CPT; ++c) pm[c] += __shfl_xor(pm[c], o);
        if ((tid & 63) < GRP) {
            #pragma unroll
            for (int c = 0; c < CPT; ++c) sPart[wid][tj + 8 * c] = pm[c];
        }
        __syncthreads();
        if (tid < L)
            sAbar[h][tid] = sPart[0][tid] + sPart[1][tid] + sPart[2][tid] + sPart[3][tid];
        __syncthreads();
    }

    float zz[NH] = {0.f, 0.f, 0.f, 0.f};
    for (int w = 0; w < L; ++w) {
        const float xw = Xs[(size_t)w * D + tid];
        #pragma unroll
        for (int h = 0; h < NH; ++h) zz[h] = fmaf(sAbar[h][w], xw, zz[h]);
    }
    #pragma unroll
    for (int h = 0; h < NH; ++h) sZ[h][tid] = zz[h];
    __syncthreads();

    {
        const int h = tid >> 6;
        float a = sCnt * bv[tid];
        #pragma unroll 8
        for (int dd = 0; dd < D; ++dd) a = fmaf(sZ[h][dd], Wv[dd * D + tid], a);
        sPP[tid] = a;
    }
    __syncthreads();

    {
        float a = 0.f;
        #pragma unroll 8
        for (int dd = 0; dd < D; ++dd) a = fmaf(sPP[dd], Wo[dd * D + tid], a);
        const float cnt = sCnt;
        Out[(size_t)seq * D + tid] = (cnt > 0.f) ? (a / cnt + bo[tid]) : 0.f;
        if (MaskOut && tid == 0) MaskOut[seq] = (cnt > 0.f) ? 1.f : 0.f;
    }
}

extern "C" void kernel_launch(void* const* d_in, const int* in_sizes, int n_in,
                              void* d_out, int out_size, void* d_ws, size_t ws_size,
                              hipStream_t stream)
{
    const float* emb  = (const float*)d_in[0];
    const int*  amask = (const int*)d_in[1];
    const float* W[24];
    for (int i = 0; i < 24; ++i) W[i] = (const float*)d_in[2 + i];
    // W[0..7] = wWq,wWk,wWv,wWo,wbq,wbk,wbv,wbo ; W[8..15] = s* ; W[16..23] = c*

    char* ws = (char*)d_ws;
    unsigned short* WT = (unsigned short*)ws;        // 256KB
    float* abar  = (float*)(ws + 256 * 1024);        // 2MB   (2048*256)
    float* cnt   = abar + 2048 * 256;                // 8KB
    float* sent  = cnt + 2048;                       // 2MB
    float* smask = sent + 2048 * 256;                // 8KB
    float* sec   = smask + 2048;                     // 128KB
    float* cmask = sec + 128 * 256;                  // 512B
    float* out   = (float*)d_out;                    // 16*256

    prep_wt<<<dim3(512), dim3(256), 0, stream>>>(W[0], W[1], WT);

    word_attn_kernel<<<dim3(2048), dim3(512), 0, stream>>>(
        emb, amask, WT, W[4], W[5], abar, cnt);
    word_apply_kernel<<<dim3(256), dim3(512), 0, stream>>>(
        emb, abar, cnt, W[2], W[3], W[6], W[7], sent, smask);

    mha_pool_kernel<16, float><<<dim3(128), dim3(256), 0, stream>>>(
        sent, smask, W[8], W[9], W[10], W[11], W[12], W[13], W[14], W[15], sec, cmask);
    mha_pool_kernel<8, float><<<dim3(16), dim3(256), 0, stream>>>(
        sec, cmask, W[16], W[17], W[18], W[19], W[20], W[21], W[22], W[23], out, nullptr);
}

// Round 4
// 191.288 us; speedup vs baseline: 4.6429x; 1.3080x over previous
//
#include <hip/hip_runtime.h>

constexpr int D = 256;

typedef __attribute__((ext_vector_type(8))) __bf16 bf16x8;
typedef __attribute__((ext_vector_type(4))) float f32x4;

__device__ inline unsigned short f2b(float f) {
    unsigned u = __builtin_bit_cast(unsigned, f);
    u = (u + 0x7fffu + ((u >> 16) & 1u)) >> 16;   // RNE
    return (unsigned short)u;
}
__device__ inline unsigned cvt_pk_bf16(float lo, float hi) {
    unsigned r;
    asm volatile("v_cvt_pk_bf16_f32 %0, %1, %2" : "=v"(r) : "v"(lo), "v"(hi));
    return r;
}
__device__ inline bf16x8 ld_frag(const void* p) {
    uint4 r = *(const uint4*)p;
    return __builtin_bit_cast(bf16x8, r);
}

// ---- prep: WT[c][k] = bf16( c<256 ? Wq[k][c] : Wk[k][c-256] ), [512][256] ----
__global__ void prep_wt(const float* __restrict__ Wq, const float* __restrict__ Wk,
                        unsigned short* __restrict__ WT) {
    const int c = blockIdx.x, k = threadIdx.x;
    const float* W = (c < 256) ? Wq : Wk;
    WT[c * 256 + k] = f2b(W[k * 256 + (c & 255)]);
}

// ================== unified attention kernel: 64 packed tokens / block ==================
// NSUB sub-sequences of LSUB=64/NSUB tokens. NSUB==1 (word): writes abar+cnt for a
// separate apply kernel. NSUB>1 (sentence/section): apply (z,pp,out) fused in-kernel.
// Scores masked to (key-valid && same-subsequence); -1e9 entries underflow to exact 0
// after exp2, so packed softmax == per-sequence softmax for every contributing row.
template<int NSUB, typename MT>
__global__ __launch_bounds__(512, 4)
void attn_kernel(const float* __restrict__ X, const MT* __restrict__ Mask,
                 const unsigned short* __restrict__ WT,
                 const float* __restrict__ bq, const float* __restrict__ bk,
                 const float* __restrict__ Wv, const float* __restrict__ Wo,
                 const float* __restrict__ bv, const float* __restrict__ bo,
                 float* __restrict__ Out0, float* __restrict__ Out1)
{
    constexpr int LSUB = 64 / NSUB;
    constexpr int L2S  = (LSUB == 64) ? 6 : (LSUB == 16) ? 4 : 3;
    constexpr int NS   = (NSUB > 1) ? NSUB : 1;

    __shared__ unsigned short sQK[64 * 512];  // 64KB: bf16 X (32KB) -> bf16 Q|K -> fp32 z-partials
    __shared__ float sM[64];
    __shared__ float sPart[8][64];
    __shared__ float sCt[NS];
    __shared__ float sAbar[4][64];
    __shared__ float sPP[NS][256];
    __shared__ float sH[2][NS][256];

    const int tid = threadIdx.x;
    const int blk = blockIdx.x;
    const float* Xs = X + (size_t)blk * 64 * D;
    char* sB = (char*)sQK;

    // ---- stage X -> bf16 LDS [64][256], pitch 512B, swizzle ((row&7)<<4); loads batched ----
    {
        const float4* X4 = (const float4*)Xs;
        float4 xv[8];
        #pragma unroll
        for (int j = 0; j < 8; ++j) xv[j] = X4[tid + j * 512];
        if (tid < 64) sM[tid] = (float)Mask[(size_t)blk * 64 + tid];
        #pragma unroll
        for (int j = 0; j < 8; ++j) {
            int i = tid + j * 512;
            int row = i >> 6, c4 = i & 63;
            uint2 pk;
            pk.x = (unsigned)f2b(xv[j].x) | ((unsigned)f2b(xv[j].y) << 16);
            pk.y = (unsigned)f2b(xv[j].z) | ((unsigned)f2b(xv[j].w) << 16);
            *(uint2*)(sB + row * 512 + ((c4 * 8) ^ ((row & 7) << 4))) = pk;
        }
    }
    __syncthreads();
    if (tid < NSUB) {
        float c = 0.f;
        for (int t = 0; t < LSUB; ++t) c += sM[tid * LSUB + t];
        sCt[tid] = c;
    }

    const int lane = tid & 63, w = tid >> 6;
    const int lr = lane & 15, lg = lane >> 4;

    // ---- proj': C[feature][token]; wave w owns features w*64..+63 (Q: w<4, K: w>=4) ----
    f32x4 acc[4][4];
    {
        const float* bias = (w < 4) ? bq : bk;
        const int fb = (w & 3) * 64;
        #pragma unroll
        for (int m = 0; m < 4; ++m) {
            float4 b4 = *(const float4*)(bias + fb + m * 16 + lg * 4);
            f32x4 bi = {b4.x, b4.y, b4.z, b4.w};
            #pragma unroll
            for (int n = 0; n < 4; ++n) acc[m][n] = bi;
        }
        const unsigned short* wtp = WT + (size_t)(w * 64 + lr) * 256 + lg * 8;
        bf16x8 afn[4];
        #pragma unroll
        for (int m = 0; m < 4; ++m) afn[m] = ld_frag(wtp + m * 16 * 256);
        #pragma unroll 1
        for (int kk = 0; kk < 8; ++kk) {
            bf16x8 af[4];
            #pragma unroll
            for (int m = 0; m < 4; ++m) af[m] = afn[m];
            if (kk < 7) {
                #pragma unroll
                for (int m = 0; m < 4; ++m) afn[m] = ld_frag(wtp + m * 16 * 256 + (kk + 1) * 32);
            }
            bf16x8 bx[4];
            #pragma unroll
            for (int n = 0; n < 4; ++n) {
                int t = n * 16 + lr;
                bx[n] = ld_frag(sB + t * 512 + ((kk * 64 + lg * 16) ^ ((t & 7) << 4)));
            }
            __builtin_amdgcn_s_setprio(1);
            #pragma unroll
            for (int m = 0; m < 4; ++m)
                #pragma unroll
                for (int n = 0; n < 4; ++n)
                    acc[m][n] = __builtin_amdgcn_mfma_f32_16x16x32_bf16(af[m], bx[n], acc[m][n], 0, 0, 0);
            __builtin_amdgcn_s_setprio(0);
        }
    }
    __syncthreads();   // all X reads done before overwrite
    // ---- writeback token-major Q|K bf16 [64][512], pitch 1024B, swizzled ----
    #pragma unroll
    for (int n = 0; n < 4; ++n) {
        int t = n * 16 + lr;
        char* rowp = sB + t * 1024;
        int sw = (t & 7) << 4;
        #pragma unroll
        for (int m = 0; m < 4; ++m) {
            uint2 pk;
            pk.x = cvt_pk_bf16(acc[m][n][0], acc[m][n][1]);
            pk.y = cvt_pk_bf16(acc[m][n][2], acc[m][n][3]);
            *(uint2*)(rowp + ((w * 128 + m * 32 + lg * 8) ^ sw)) = pk;
        }
    }
    __syncthreads();

    // ---- scores + softmax + abar; h = w>>1, query rows msel*32..+31 ----
    {
        const int h = w >> 1, msel = w & 1;
        f32x4 sacc[2][4];
        #pragma unroll
        for (int m = 0; m < 2; ++m)
            #pragma unroll
            for (int n = 0; n < 4; ++n) sacc[m][n] = (f32x4){0.f, 0.f, 0.f, 0.f};
        #pragma unroll
        for (int kk = 0; kk < 2; ++kk) {
            bf16x8 qf[2];
            #pragma unroll
            for (int m = 0; m < 2; ++m) {
                int t = msel * 32 + m * 16 + lr;
                qf[m] = ld_frag(sB + t * 1024 + ((h * 128 + kk * 64 + lg * 16) ^ ((t & 7) << 4)));
            }
            #pragma unroll
            for (int n = 0; n < 4; ++n) {
                int t = n * 16 + lr;
                bf16x8 kf = ld_frag(sB + t * 1024 + ((512 + h * 128 + kk * 64 + lg * 16) ^ ((t & 7) << 4)));
                #pragma unroll
                for (int m = 0; m < 2; ++m)
                    sacc[m][n] = __builtin_amdgcn_mfma_f32_16x16x32_bf16(qf[m], kf, sacc[m][n], 0, 0, 0);
            }
        }
        float mcol[4];
        int csub[4];
        #pragma unroll
        for (int n = 0; n < 4; ++n) {
            mcol[n] = sM[n * 16 + lr];
            csub[n] = (n * 16 + lr) >> L2S;
        }
        constexpr float CE = 0.125f * 1.44269504f;   // fold 1/sqrt(dh) into exp2
        float pm[4] = {0.f, 0.f, 0.f, 0.f};
        #pragma unroll
        for (int m = 0; m < 2; ++m)
            #pragma unroll
            for (int r = 0; r < 4; ++r) {
                const int rowtok = msel * 32 + m * 16 + lg * 4 + r;
                const int rsub = rowtok >> L2S;
                float s[4], mx = -3.4e38f;
                #pragma unroll
                for (int n = 0; n < 4; ++n) {
                    float v = sacc[m][n][r];
                    bool ok = (mcol[n] > 0.f);
                    if constexpr (NSUB > 1) ok = ok && (csub[n] == rsub);
                    v = ok ? v : -1e9f;
                    s[n] = v; mx = fmaxf(mx, v);
                }
                #pragma unroll
                for (int o = 1; o < 16; o <<= 1) mx = fmaxf(mx, __shfl_xor(mx, o));
                float e[4], se = 0.f;
                #pragma unroll
                for (int n = 0; n < 4; ++n) { e[n] = exp2f((s[n] - mx) * CE); se += e[n]; }
                #pragma unroll
                for (int o = 1; o < 16; o <<= 1) se += __shfl_xor(se, o);
                const float wr = sM[rowtok] / se;    // query-mask * (1/rowsum)
                #pragma unroll
                for (int n = 0; n < 4; ++n) pm[n] += e[n] * wr;
            }
        #pragma unroll
        for (int o = 16; o < 64; o <<= 1)
            #pragma unroll
            for (int n = 0; n < 4; ++n) pm[n] += __shfl_xor(pm[n], o);
        if (lane < 16)
            #pragma unroll
            for (int n = 0; n < 4; ++n) sPart[w][n * 16 + lane] = pm[n];
    }
    __syncthreads();

    if constexpr (NSUB == 1) {
        if (tid < 256) {
            int h = tid >> 6, j = tid & 63;
            Out0[(size_t)blk * 256 + tid] = sPart[2 * h][j] + sPart[2 * h + 1][j];
        }
        if (tid == 0) Out1[blk] = sCt[0];
    } else {
        if (tid < 256) {
            int h = tid >> 6, j = tid & 63;
            sAbar[h][j] = sPart[2 * h][j] + sPart[2 * h + 1][j];
        }
        __syncthreads();
        // ---- z partials (fp32 X from global, L2-resident) into sQK reused as float ----
        float* zp = (float*)sB;    // [2][NSUB][4][256]
        const int d = tid & 255, rh = tid >> 8;
        constexpr int HT = LSUB / 2;
        #pragma unroll
        for (int s = 0; s < NSUB; ++s) {
            float zz[4] = {0.f, 0.f, 0.f, 0.f};
            const int t0 = s * LSUB + rh * HT;
            #pragma unroll
            for (int t = 0; t < HT; ++t) {
                float xv = Xs[(size_t)(t0 + t) * 256 + d];
                #pragma unroll
                for (int h = 0; h < 4; ++h) zz[h] = fmaf(sAbar[h][t0 + t], xv, zz[h]);
            }
            #pragma unroll
            for (int h = 0; h < 4; ++h) zp[((rh * NSUB + s) * 4 + h) * 256 + d] = zz[h];
        }
        __syncthreads();
        // ---- pp = z @ Wv + cnt*bv ----
        {
            const int n = tid & 255, g = tid >> 8, h = n >> 6;
            float pa[NSUB];
            #pragma unroll
            for (int s = 0; s < NSUB; ++s) pa[s] = 0.f;
            for (int dc = 0; dc < 128; dc += 8) {
                float wv[8];
                #pragma unroll
                for (int q = 0; q < 8; ++q) wv[q] = Wv[(size_t)(g * 128 + dc + q) * 256 + n];
                #pragma unroll
                for (int s = 0; s < NSUB; ++s)
                    #pragma unroll
                    for (int q = 0; q < 8; ++q) {
                        int dd = g * 128 + dc + q;
                        float zv = zp[(s * 4 + h) * 256 + dd] + zp[((NSUB + s) * 4 + h) * 256 + dd];
                        pa[s] = fmaf(zv, wv[q], pa[s]);
                    }
            }
            #pragma unroll
            for (int s = 0; s < NSUB; ++s) sH[g][s][n] = pa[s];
        }
        __syncthreads();
        for (int i = tid; i < NSUB * 256; i += 512) {
            int s = i >> 8, nn = i & 255;
            sPP[s][nn] = sH[0][s][nn] + sH[1][s][nn] + sCt[s] * bv[nn];
        }
        __syncthreads();
        // ---- out = pp @ Wo / cnt + bo ----
        {
            const int n = tid & 255, g = tid >> 8;
            float pa[NSUB];
            #pragma unroll
            for (int s = 0; s < NSUB; ++s) pa[s] = 0.f;
            for (int dc = 0; dc < 128; dc += 8) {
                float wo[8];
                #pragma unroll
                for (int q = 0; q < 8; ++q) wo[q] = Wo[(size_t)(g * 128 + dc + q) * 256 + n];
                #pragma unroll
                for (int s = 0; s < NSUB; ++s) {
                    const float* pp = &sPP[s][g * 128 + dc];
                    #pragma unroll
                    for (int q = 0; q < 8; ++q) pa[s] = fmaf(pp[q], wo[q], pa[s]);
                }
            }
            #pragma unroll
            for (int s = 0; s < NSUB; ++s) sH[g][s][n] = pa[s];
        }
        __syncthreads();
        for (int i = tid; i < NSUB * 256; i += 512) {
            int s = i >> 8, nn = i & 255;
            float c = sCt[s];
            Out0[(size_t)(blk * NSUB + s) * 256 + nn] =
                (c > 0.f) ? ((sH[0][s][nn] + sH[1][s][nn]) / c + bo[nn]) : 0.f;
        }
        if (tid < NSUB && Out1) Out1[blk * NSUB + tid] = (sCt[tid] > 0.f) ? 1.f : 0.f;
    }
}

// =============== word apply: z = abar@X ; pp = z@Wv + cnt*bv ; out = pp@Wo/cnt + bo ===============
__global__ __launch_bounds__(512, 4)
void word_apply_kernel(const float* __restrict__ X, const float* __restrict__ Abar,
                       const float* __restrict__ Cnt,
                       const float* __restrict__ Wv, const float* __restrict__ Wo,
                       const float* __restrict__ bv, const float* __restrict__ bo,
                       float* __restrict__ Out, float* __restrict__ MaskOut)
{
    constexpr int SPB = 4;
    __shared__ float sAb[SPB][4][64];   // 4KB
    __shared__ float sZ[SPB][4][256];   // 16KB
    __shared__ float sPP[SPB][256];     // 4KB
    __shared__ float sH[2][SPB][256];   // 8KB
    __shared__ float sCt[SPB];

    const int tid = threadIdx.x;
    const int s0 = blockIdx.x * SPB;

    for (int i = tid; i < SPB * 256; i += 512)
        sAb[i >> 8][(i >> 6) & 3][i & 63] = Abar[(size_t)s0 * 256 + i];
    if (tid < SPB) sCt[tid] = Cnt[s0 + tid];
    __syncthreads();

    const int d = tid & 255, rh = tid >> 8;

    {
        float zz[SPB][4];
        #pragma unroll
        for (int s = 0; s < SPB; ++s) {
            const float* xp = X + ((size_t)(s0 + s) * 64 + rh * 32) * 256 + d;
            const float* ab0 = &sAb[s][0][rh * 32];
            const float* ab1 = &sAb[s][1][rh * 32];
            const float* ab2 = &sAb[s][2][rh * 32];
            const float* ab3 = &sAb[s][3][rh * 32];
            float a0 = 0.f, a1 = 0.f, a2 = 0.f, a3 = 0.f;
            #pragma unroll 8
            for (int t = 0; t < 32; ++t) {
                float xv = xp[t * 256];
                a0 = fmaf(ab0[t], xv, a0);
                a1 = fmaf(ab1[t], xv, a1);
                a2 = fmaf(ab2[t], xv, a2);
                a3 = fmaf(ab3[t], xv, a3);
            }
            zz[s][0] = a0; zz[s][1] = a1; zz[s][2] = a2; zz[s][3] = a3;
        }
        if (rh == 0) {
            #pragma unroll
            for (int s = 0; s < SPB; ++s)
                #pragma unroll
                for (int h = 0; h < 4; ++h) sZ[s][h][d] = zz[s][h];
        }
        __syncthreads();
        if (rh == 1) {
            #pragma unroll
            for (int s = 0; s < SPB; ++s)
                #pragma unroll
                for (int h = 0; h < 4; ++h) sZ[s][h][d] += zz[s][h];
        }
        __syncthreads();
    }

    const int n = d, g = rh, h = n >> 6;

    {
        float pa[SPB];
        #pragma unroll
        for (int s = 0; s < SPB; ++s) pa[s] = 0.f;
        for (int dc = 0; dc < 128; dc += 16) {
            float wv[16];
            #pragma unroll
            for (int q = 0; q < 16; ++q) wv[q] = Wv[(size_t)(g * 128 + dc + q) * 256 + n];
            #pragma unroll
            for (int s = 0; s < SPB; ++s) {
                const float4* zpv = (const float4*)&sZ[s][h][g * 128 + dc];
                #pragma unroll
                for (int q4 = 0; q4 < 4; ++q4) {
                    float4 zv = zpv[q4];
                    pa[s] = fmaf(zv.x, wv[q4 * 4 + 0], pa[s]);
                    pa[s] = fmaf(zv.y, wv[q4 * 4 + 1], pa[s]);
                    pa[s] = fmaf(zv.z, wv[q4 * 4 + 2], pa[s]);
                    pa[s] = fmaf(zv.w, wv[q4 * 4 + 3], pa[s]);
                }
            }
        }
        #pragma unroll
        for (int s = 0; s < SPB; ++s) sH[g][s][n] = pa[s];
    }
    __syncthreads();
    for (int i = tid; i < SPB * 256; i += 512) {
        int s = i >> 8, nn = i & 255;
        sPP[s][nn] = sH[0][s][nn] + sH[1][s][nn] + sCt[s] * bv[nn];
    }
    __syncthreads();

    {
        float pa[SPB];
        #pragma unroll
        for (int s = 0; s < SPB; ++s) pa[s] = 0.f;
        for (int dc = 0; dc < 128; dc += 16) {
            float wo[16];
            #pragma unroll
            for (int q = 0; q < 16; ++q) wo[q] = Wo[(size_t)(g * 128 + dc + q) * 256 + n];
            #pragma unroll
            for (int s = 0; s < SPB; ++s) {
                const float4* pp = (const float4*)&sPP[s][g * 128 + dc];
                #pragma unroll
                for (int q4 = 0; q4 < 4; ++q4) {
                    float4 pv = pp[q4];
                    pa[s] = fmaf(pv.x, wo[q4 * 4 + 0], pa[s]);
                    pa[s] = fmaf(pv.y, wo[q4 * 4 + 1], pa[s]);
                    pa[s] = fmaf(pv.z, wo[q4 * 4 + 2], pa[s]);
                    pa[s] = fmaf(pv.w, wo[q4 * 4 + 3], pa[s]);
                }
            }
        }
        #pragma unroll
        for (int s = 0; s < SPB; ++s) sH[g][s][n] = pa[s];
    }
    __syncthreads();
    for (int i = tid; i < SPB * 256; i += 512) {
        int s = i >> 8, nn = i & 255;
        float c = sCt[s];
        Out[(size_t)(s0 + s) * 256 + nn] = (c > 0.f) ? ((sH[0][s][nn] + sH[1][s][nn]) / c + bo[nn]) : 0.f;
    }
    if (tid < SPB && MaskOut) MaskOut[s0 + tid] = (sCt[tid] > 0.f) ? 1.f : 0.f;
}

extern "C" void kernel_launch(void* const* d_in, const int* in_sizes, int n_in,
                              void* d_out, int out_size, void* d_ws, size_t ws_size,
                              hipStream_t stream)
{
    const float* emb  = (const float*)d_in[0];
    const int*  amask = (const int*)d_in[1];
    const float* W[24];
    for (int i = 0; i < 24; ++i) W[i] = (const float*)d_in[2 + i];
    // W[0..7] = wWq,wWk,wWv,wWo,wbq,wbk,wbv,wbo ; W[8..15] = s* ; W[16..23] = c*

    char* ws = (char*)d_ws;
    unsigned short* WTw = (unsigned short*)ws;       // 256KB
    unsigned short* WTs = WTw + 512 * 256;           // 256KB
    unsigned short* WTc = WTs + 512 * 256;           // 256KB
    float* abar  = (float*)(ws + 3 * 256 * 1024);    // 2MB
    float* cnt   = abar + 2048 * 256;                // 8KB
    float* sent  = cnt + 2048;                       // 2MB
    float* smask = sent + 2048 * 256;                // 8KB
    float* sec   = smask + 2048;                     // 128KB
    float* cmask = sec + 128 * 256;                  // 512B
    float* out   = (float*)d_out;                    // 16*256

    prep_wt<<<dim3(512), dim3(256), 0, stream>>>(W[0], W[1], WTw);
    prep_wt<<<dim3(512), dim3(256), 0, stream>>>(W[8], W[9], WTs);
    prep_wt<<<dim3(512), dim3(256), 0, stream>>>(W[16], W[17], WTc);

    // word level: attn (2048 blocks) + apply (512 blocks)
    attn_kernel<1, int><<<dim3(2048), dim3(512), 0, stream>>>(
        emb, amask, WTw, W[4], W[5], nullptr, nullptr, nullptr, nullptr, abar, cnt);
    word_apply_kernel<<<dim3(512), dim3(512), 0, stream>>>(
        emb, abar, cnt, W[2], W[3], W[6], W[7], sent, smask);

    // sentence level: 128 seqs of 16 -> 32 packed blocks (apply fused)
    attn_kernel<4, float><<<dim3(32), dim3(512), 0, stream>>>(
        sent, smask, WTs, W[12], W[13], W[10], W[11], W[14], W[15], sec, cmask);

    // section level: 16 seqs of 8 -> 2 packed blocks (apply fused)
    attn_kernel<8, float><<<dim3(2), dim3(512), 0, stream>>>(
        sec, cmask, WTc, W[20], W[21], W[18], W[19], W[22], W[23], out, nullptr);
}

// Round 5
// 183.353 us; speedup vs baseline: 4.8439x; 1.0433x over previous
//
#include <hip/hip_runtime.h>

constexpr int D = 256;

typedef __attribute__((ext_vector_type(8))) __bf16 bf16x8;
typedef __attribute__((ext_vector_type(4))) float f32x4;

__device__ inline unsigned short f2b(float f) {
    unsigned u = __builtin_bit_cast(unsigned, f);
    u = (u + 0x7fffu + ((u >> 16) & 1u)) >> 16;   // RNE
    return (unsigned short)u;
}
__device__ inline unsigned cvt_pk_bf16(float lo, float hi) {
    unsigned r;
    asm volatile("v_cvt_pk_bf16_f32 %0, %1, %2" : "=v"(r) : "v"(lo), "v"(hi));
    return r;
}
__device__ inline bf16x8 ld_frag(const void* p) {
    uint4 r = *(const uint4*)p;
    return __builtin_bit_cast(bf16x8, r);
}

// ---- prep (all 3 levels): WT[lvl][c][k] = bf16( c<256 ? Wq[k][c] : Wk[k][c-256] ) ----
__global__ void prep_wt3(const float* __restrict__ q0, const float* __restrict__ k0,
                         const float* __restrict__ q1, const float* __restrict__ k1,
                         const float* __restrict__ q2, const float* __restrict__ k2,
                         unsigned short* __restrict__ WT) {
    const int b = blockIdx.x, k = threadIdx.x;
    const int lvl = b >> 9, c = b & 511;
    const float* Wq = (lvl == 0) ? q0 : (lvl == 1) ? q1 : q2;
    const float* Wk = (lvl == 0) ? k0 : (lvl == 1) ? k1 : k2;
    const float* W = (c < 256) ? Wq : Wk;
    WT[(size_t)b * 256 + k] = f2b(W[k * 256 + (c & 255)]);
}

// ================== unified attention kernel: 64 packed tokens / block ==================
// NSUB sub-seqs of LSUB=64/NSUB tokens. NSUB==1 (word): computes Z[blk][4][256] = abar@X
// from the held bf16-X registers (no second X pass) + Cnt. NSUB>1: full apply fused.
template<int NSUB, typename MT>
__global__ __launch_bounds__(512, 4)
void attn_kernel(const float* __restrict__ X, const MT* __restrict__ Mask,
                 const unsigned short* __restrict__ WT,
                 const float* __restrict__ bq, const float* __restrict__ bk,
                 const float* __restrict__ Wv, const float* __restrict__ Wo,
                 const float* __restrict__ bv, const float* __restrict__ bo,
                 float* __restrict__ Out0, float* __restrict__ Out1)
{
    constexpr int LSUB = 64 / NSUB;
    constexpr int L2S  = (LSUB == 64) ? 6 : (LSUB == 16) ? 4 : 3;
    constexpr int NS   = (NSUB > 1) ? NSUB : 1;

    __shared__ unsigned short sQK[64 * 512];  // 64KB: bf16 X -> bf16 Q|K -> fp32 z partials
    __shared__ float sM[64];
    __shared__ float sPart[8][64];
    __shared__ float sCt[NS];
    __shared__ float sAbarT[64][4];           // NSUB==1: token-major abar
    __shared__ float sAbar[4][64];            // NSUB>1
    __shared__ float sPP[NS][256];
    __shared__ float sH[2][NS][256];

    const int tid = threadIdx.x;
    const int blk = blockIdx.x;
    const float* Xs = X + (size_t)blk * 64 * D;
    char* sB = (char*)sQK;
    const int lane = tid & 63, w = tid >> 6;
    const int lr = lane & 15, lg = lane >> 4;

    // ---- stage X -> bf16 LDS [64][256], pitch 512B, swizzle ((row&7)<<4); keep pk in regs ----
    uint2 pk[8];
    {
        const float4* X4 = (const float4*)Xs;
        float4 xv[8];
        #pragma unroll
        for (int j = 0; j < 8; ++j) xv[j] = X4[tid + j * 512];
        if (tid < 64) sM[tid] = (float)Mask[(size_t)blk * 64 + tid];
        #pragma unroll
        for (int j = 0; j < 8; ++j) {
            pk[j].x = cvt_pk_bf16(xv[j].x, xv[j].y);
            pk[j].y = cvt_pk_bf16(xv[j].z, xv[j].w);
            const int row = w + 8 * j;      // == (tid + j*512) >> 6
            *(uint2*)(sB + row * 512 + ((lane * 8) ^ ((row & 7) << 4))) = pk[j];
        }
    }
    __syncthreads();
    // ---- per-subseq counts: wave-parallel segmented reduce ----
    if (tid < 64) {
        float v = sM[tid];
        #pragma unroll
        for (int o = 1; o < LSUB; o <<= 1) v += __shfl_xor(v, o);
        if ((tid & (LSUB - 1)) == 0) sCt[tid >> L2S] = v;
    }

    // ---- proj': C[feature][token]; wave w owns features w*64..+63 (Q: w<4, K: w>=4) ----
    f32x4 acc[4][4];
    {
        const float* bias = (w < 4) ? bq : bk;
        const int fb = (w & 3) * 64;
        #pragma unroll
        for (int m = 0; m < 4; ++m) {
            float4 b4 = *(const float4*)(bias + fb + m * 16 + lg * 4);
            f32x4 bi = {b4.x, b4.y, b4.z, b4.w};
            #pragma unroll
            for (int n = 0; n < 4; ++n) acc[m][n] = bi;
        }
        const unsigned short* wtp = WT + (size_t)(w * 64 + lr) * 256 + lg * 8;
        bf16x8 afn[4];
        #pragma unroll
        for (int m = 0; m < 4; ++m) afn[m] = ld_frag(wtp + m * 16 * 256);
        #pragma unroll 1
        for (int kk = 0; kk < 8; ++kk) {
            bf16x8 af[4];
            #pragma unroll
            for (int m = 0; m < 4; ++m) af[m] = afn[m];
            if (kk < 7) {
                #pragma unroll
                for (int m = 0; m < 4; ++m) afn[m] = ld_frag(wtp + m * 16 * 256 + (kk + 1) * 32);
            }
            bf16x8 bx[4];
            #pragma unroll
            for (int n = 0; n < 4; ++n) {
                int t = n * 16 + lr;
                bx[n] = ld_frag(sB + t * 512 + ((kk * 64 + lg * 16) ^ ((t & 7) << 4)));
            }
            __builtin_amdgcn_s_setprio(1);
            #pragma unroll
            for (int m = 0; m < 4; ++m)
                #pragma unroll
                for (int n = 0; n < 4; ++n)
                    acc[m][n] = __builtin_amdgcn_mfma_f32_16x16x32_bf16(af[m], bx[n], acc[m][n], 0, 0, 0);
            __builtin_amdgcn_s_setprio(0);
        }
    }
    __syncthreads();   // all X reads done before overwrite
    // ---- writeback token-major Q|K bf16 [64][512], pitch 1024B, swizzled ----
    #pragma unroll
    for (int n = 0; n < 4; ++n) {
        int t = n * 16 + lr;
        char* rowp = sB + t * 1024;
        int sw = (t & 7) << 4;
        #pragma unroll
        for (int m = 0; m < 4; ++m) {
            uint2 qk;
            qk.x = cvt_pk_bf16(acc[m][n][0], acc[m][n][1]);
            qk.y = cvt_pk_bf16(acc[m][n][2], acc[m][n][3]);
            *(uint2*)(rowp + ((w * 128 + m * 32 + lg * 8) ^ sw)) = qk;
        }
    }
    __syncthreads();

    // ---- scores + softmax + abar; h = w>>1, query rows msel*32..+31 ----
    {
        const int h = w >> 1, msel = w & 1;
        f32x4 sacc[2][4];
        #pragma unroll
        for (int m = 0; m < 2; ++m)
            #pragma unroll
            for (int n = 0; n < 4; ++n) sacc[m][n] = (f32x4){0.f, 0.f, 0.f, 0.f};
        #pragma unroll
        for (int kk = 0; kk < 2; ++kk) {
            bf16x8 qf[2];
            #pragma unroll
            for (int m = 0; m < 2; ++m) {
                int t = msel * 32 + m * 16 + lr;
                qf[m] = ld_frag(sB + t * 1024 + ((h * 128 + kk * 64 + lg * 16) ^ ((t & 7) << 4)));
            }
            #pragma unroll
            for (int n = 0; n < 4; ++n) {
                int t = n * 16 + lr;
                bf16x8 kf = ld_frag(sB + t * 1024 + ((512 + h * 128 + kk * 64 + lg * 16) ^ ((t & 7) << 4)));
                #pragma unroll
                for (int m = 0; m < 2; ++m)
                    sacc[m][n] = __builtin_amdgcn_mfma_f32_16x16x32_bf16(qf[m], kf, sacc[m][n], 0, 0, 0);
            }
        }
        float mcol[4];
        int csub[4];
        #pragma unroll
        for (int n = 0; n < 4; ++n) {
            mcol[n] = sM[n * 16 + lr];
            csub[n] = (n * 16 + lr) >> L2S;
        }
        constexpr float CE = 0.125f * 1.44269504f;   // fold 1/sqrt(dh) into exp2
        float pm[4] = {0.f, 0.f, 0.f, 0.f};
        #pragma unroll
        for (int m = 0; m < 2; ++m)
            #pragma unroll
            for (int r = 0; r < 4; ++r) {
                const int rowtok = msel * 32 + m * 16 + lg * 4 + r;
                const int rsub = rowtok >> L2S;
                float s[4], mx = -3.4e38f;
                #pragma unroll
                for (int n = 0; n < 4; ++n) {
                    float v = sacc[m][n][r];
                    bool ok = (mcol[n] > 0.f);
                    if constexpr (NSUB > 1) ok = ok && (csub[n] == rsub);
                    v = ok ? v : -1e9f;
                    s[n] = v; mx = fmaxf(mx, v);
                }
                #pragma unroll
                for (int o = 1; o < 16; o <<= 1) mx = fmaxf(mx, __shfl_xor(mx, o));
                float e[4], se = 0.f;
                #pragma unroll
                for (int n = 0; n < 4; ++n) { e[n] = exp2f((s[n] - mx) * CE); se += e[n]; }
                #pragma unroll
                for (int o = 1; o < 16; o <<= 1) se += __shfl_xor(se, o);
                const float wr = sM[rowtok] / se;    // query-mask * (1/rowsum)
                #pragma unroll
                for (int n = 0; n < 4; ++n) pm[n] += e[n] * wr;
            }
        #pragma unroll
        for (int o = 16; o < 64; o <<= 1)
            #pragma unroll
            for (int n = 0; n < 4; ++n) pm[n] += __shfl_xor(pm[n], o);
        if (lane < 16)
            #pragma unroll
            for (int n = 0; n < 4; ++n) sPart[w][n * 16 + lane] = pm[n];
    }
    __syncthreads();

    if constexpr (NSUB == 1) {
        // ---- abar (token-major, fp32) ----
        if (tid < 256) {
            int h = tid >> 6, j = tid & 63;
            sAbarT[j][h] = sPart[2 * h][j] + sPart[2 * h + 1][j];
        }
        __syncthreads();
        // ---- per-thread z partials from held bf16-X regs: tokens w+8j, feats lane*4..+3 ----
        float zp[4][4];
        #pragma unroll
        for (int h = 0; h < 4; ++h)
            #pragma unroll
            for (int e = 0; e < 4; ++e) zp[h][e] = 0.f;
        #pragma unroll
        for (int j = 0; j < 8; ++j) {
            const int t = w + 8 * j;
            f32x4 ab = *(const f32x4*)&sAbarT[t][0];   // broadcast (uniform addr per wave)
            float x0 = __builtin_bit_cast(float, pk[j].x << 16);
            float x1 = __builtin_bit_cast(float, pk[j].x & 0xffff0000u);
            float x2 = __builtin_bit_cast(float, pk[j].y << 16);
            float x3 = __builtin_bit_cast(float, pk[j].y & 0xffff0000u);
            #pragma unroll
            for (int h = 0; h < 4; ++h) {
                zp[h][0] = fmaf(ab[h], x0, zp[h][0]);
                zp[h][1] = fmaf(ab[h], x1, zp[h][1]);
                zp[h][2] = fmaf(ab[h], x2, zp[h][2]);
                zp[h][3] = fmaf(ab[h], x3, zp[h][3]);
            }
        }
        // ---- cross-wave reduce through freed sQK (slot-swizzled to spread banks) ----
        #pragma unroll
        for (int h = 0; h < 4; ++h) {
            const int slot = (h + (lane >> 2)) & 3;
            *(f32x4*)(sB + (size_t)(w * 64 + lane) * 64 + slot * 16) =
                (f32x4){zp[h][0], zp[h][1], zp[h][2], zp[h][3]};
        }
        __syncthreads();
        {
            const int d = tid & 255, hp = (tid >> 8) * 2;
            const int ln = d >> 2, e = d & 3;
            const int s0_ = (hp + (ln >> 2)) & 3;
            const int s1_ = (hp + 1 + (ln >> 2)) & 3;
            float a0 = 0.f, a1 = 0.f;
            #pragma unroll
            for (int ww = 0; ww < 8; ++ww) {
                const float* pb = (const float*)(sB + (size_t)(ww * 64 + ln) * 64);
                a0 += pb[s0_ * 4 + e];
                a1 += pb[s1_ * 4 + e];
            }
            float* Zo = Out0 + (size_t)blk * 1024;
            Zo[hp * 256 + d] = a0;
            Zo[(hp + 1) * 256 + d] = a1;
        }
        if (tid == 0) Out1[blk] = sCt[0];
    } else {
        if (tid < 256) {
            int h = tid >> 6, j = tid & 63;
            sAbar[h][j] = sPart[2 * h][j] + sPart[2 * h + 1][j];
        }
        __syncthreads();
        // ---- z partials (fp32 X from global, L2-resident) into sQK reused as float ----
        float* zpf = (float*)sB;    // [2][NSUB][4][256]
        const int d = tid & 255, rh = tid >> 8;
        constexpr int HT = LSUB / 2;
        #pragma unroll
        for (int s = 0; s < NSUB; ++s) {
            float zz[4] = {0.f, 0.f, 0.f, 0.f};
            const int t0 = s * LSUB + rh * HT;
            #pragma unroll
            for (int t = 0; t < HT; ++t) {
                float xv = Xs[(size_t)(t0 + t) * 256 + d];
                #pragma unroll
                for (int h = 0; h < 4; ++h) zz[h] = fmaf(sAbar[h][t0 + t], xv, zz[h]);
            }
            #pragma unroll
            for (int h = 0; h < 4; ++h) zpf[((rh * NSUB + s) * 4 + h) * 256 + d] = zz[h];
        }
        __syncthreads();
        // ---- pp = z @ Wv + cnt*bv ----
        {
            const int n = tid & 255, g = tid >> 8, h = n >> 6;
            float pa[NSUB];
            #pragma unroll
            for (int s = 0; s < NSUB; ++s) pa[s] = 0.f;
            for (int dc = 0; dc < 128; dc += 8) {
                float wv[8];
                #pragma unroll
                for (int q = 0; q < 8; ++q) wv[q] = Wv[(size_t)(g * 128 + dc + q) * 256 + n];
                #pragma unroll
                for (int s = 0; s < NSUB; ++s)
                    #pragma unroll
                    for (int q = 0; q < 8; ++q) {
                        int dd = g * 128 + dc + q;
                        float zv = zpf[(s * 4 + h) * 256 + dd] + zpf[((NSUB + s) * 4 + h) * 256 + dd];
                        pa[s] = fmaf(zv, wv[q], pa[s]);
                    }
            }
            #pragma unroll
            for (int s = 0; s < NSUB; ++s) sH[g][s][n] = pa[s];
        }
        __syncthreads();
        for (int i = tid; i < NSUB * 256; i += 512) {
            int s = i >> 8, nn = i & 255;
            sPP[s][nn] = sH[0][s][nn] + sH[1][s][nn] + sCt[s] * bv[nn];
        }
        __syncthreads();
        // ---- out = pp @ Wo / cnt + bo ----
        {
            const int n = tid & 255, g = tid >> 8;
            float pa[NSUB];
            #pragma unroll
            for (int s = 0; s < NSUB; ++s) pa[s] = 0.f;
            for (int dc = 0; dc < 128; dc += 8) {
                float wo[8];
                #pragma unroll
                for (int q = 0; q < 8; ++q) wo[q] = Wo[(size_t)(g * 128 + dc + q) * 256 + n];
                #pragma unroll
                for (int s = 0; s < NSUB; ++s) {
                    const float* pp = &sPP[s][g * 128 + dc];
                    #pragma unroll
                    for (int q = 0; q < 8; ++q) pa[s] = fmaf(pp[q], wo[q], pa[s]);
                }
            }
            #pragma unroll
            for (int s = 0; s < NSUB; ++s) sH[g][s][n] = pa[s];
        }
        __syncthreads();
        for (int i = tid; i < NSUB * 256; i += 512) {
            int s = i >> 8, nn = i & 255;
            float c = sCt[s];
            Out0[(size_t)(blk * NSUB + s) * 256 + nn] =
                (c > 0.f) ? ((sH[0][s][nn] + sH[1][s][nn]) / c + bo[nn]) : 0.f;
        }
        if (tid < NSUB && Out1) Out1[blk * NSUB + tid] = (sCt[tid] > 0.f) ? 1.f : 0.f;
    }
}

// =============== apply2: pp = Z@Wv + cnt*bv ; out = pp@Wo/cnt + bo  (no X pass) ===============
__global__ __launch_bounds__(512, 4)
void apply2(const float* __restrict__ Z, const float* __restrict__ Cnt,
            const float* __restrict__ Wv, const float* __restrict__ Wo,
            const float* __restrict__ bv, const float* __restrict__ bo,
            float* __restrict__ Out, float* __restrict__ MaskOut)
{
    constexpr int SPB = 4;
    __shared__ float sZ[SPB][4][256];   // 16KB
    __shared__ float sPP[SPB][256];     // 4KB
    __shared__ float sH[2][SPB][256];   // 8KB
    __shared__ float sCt[SPB];

    const int tid = threadIdx.x;
    const int s0 = blockIdx.x * SPB;
    {
        const float4* Zf = (const float4*)(Z + (size_t)s0 * 1024);
        float4* sZf = (float4*)sZ;
        #pragma unroll
        for (int k = 0; k < 2; ++k) sZf[tid + k * 512] = Zf[tid + k * 512];
        if (tid < SPB) sCt[tid] = Cnt[s0 + tid];
    }
    __syncthreads();

    const int n = tid & 255, g = tid >> 8, h = n >> 6;

    {
        float pa[SPB] = {0.f, 0.f, 0.f, 0.f};
        for (int dc = 0; dc < 128; dc += 16) {
            float wv[16];
            #pragma unroll
            for (int q = 0; q < 16; ++q) wv[q] = Wv[(size_t)(g * 128 + dc + q) * 256 + n];
            #pragma unroll
            for (int s = 0; s < SPB; ++s) {
                const float4* zp4 = (const float4*)&sZ[s][h][g * 128 + dc];
                #pragma unroll
                for (int q4 = 0; q4 < 4; ++q4) {
                    float4 zv = zp4[q4];
                    pa[s] = fmaf(zv.x, wv[q4 * 4 + 0], pa[s]);
                    pa[s] = fmaf(zv.y, wv[q4 * 4 + 1], pa[s]);
                    pa[s] = fmaf(zv.z, wv[q4 * 4 + 2], pa[s]);
                    pa[s] = fmaf(zv.w, wv[q4 * 4 + 3], pa[s]);
                }
            }
        }
        #pragma unroll
        for (int s = 0; s < SPB; ++s) sH[g][s][n] = pa[s];
    }
    __syncthreads();
    for (int i = tid; i < SPB * 256; i += 512) {
        int s = i >> 8, nn = i & 255;
        sPP[s][nn] = sH[0][s][nn] + sH[1][s][nn] + sCt[s] * bv[nn];
    }
    __syncthreads();
    {
        float pa[SPB] = {0.f, 0.f, 0.f, 0.f};
        for (int dc = 0; dc < 128; dc += 16) {
            float wo[16];
            #pragma unroll
            for (int q = 0; q < 16; ++q) wo[q] = Wo[(size_t)(g * 128 + dc + q) * 256 + n];
            #pragma unroll
            for (int s = 0; s < SPB; ++s) {
                const float4* pp = (const float4*)&sPP[s][g * 128 + dc];
                #pragma unroll
                for (int q4 = 0; q4 < 4; ++q4) {
                    float4 pv = pp[q4];
                    pa[s] = fmaf(pv.x, wo[q4 * 4 + 0], pa[s]);
                    pa[s] = fmaf(pv.y, wo[q4 * 4 + 1], pa[s]);
                    pa[s] = fmaf(pv.z, wo[q4 * 4 + 2], pa[s]);
                    pa[s] = fmaf(pv.w, wo[q4 * 4 + 3], pa[s]);
                }
            }
        }
        #pragma unroll
        for (int s = 0; s < SPB; ++s) sH[g][s][n] = pa[s];
    }
    __syncthreads();
    for (int i = tid; i < SPB * 256; i += 512) {
        int s = i >> 8, nn = i & 255;
        float c = sCt[s];
        Out[(size_t)(s0 + s) * 256 + nn] = (c > 0.f) ? ((sH[0][s][nn] + sH[1][s][nn]) / c + bo[nn]) : 0.f;
    }
    if (tid < SPB && MaskOut) MaskOut[s0 + tid] = (sCt[tid] > 0.f) ? 1.f : 0.f;
}

extern "C" void kernel_launch(void* const* d_in, const int* in_sizes, int n_in,
                              void* d_out, int out_size, void* d_ws, size_t ws_size,
                              hipStream_t stream)
{
    const float* emb  = (const float*)d_in[0];
    const int*  amask = (const int*)d_in[1];
    const float* W[24];
    for (int i = 0; i < 24; ++i) W[i] = (const float*)d_in[2 + i];
    // W[0..7] = wWq,wWk,wWv,wWo,wbq,wbk,wbv,wbo ; W[8..15] = s* ; W[16..23] = c*

    char* ws = (char*)d_ws;
    unsigned short* WT = (unsigned short*)ws;        // 3 * 512*256 * 2B = 768KB
    float* zbuf  = (float*)(ws + 3 * 256 * 1024);    // 2048*4*256 = 8MB
    float* cnt   = zbuf + 2048 * 1024;               // 8KB
    float* sent  = cnt + 2048;                       // 2MB
    float* smask = sent + 2048 * 256;                // 8KB
    float* sec   = smask + 2048;                     // 128KB
    float* cmask = sec + 128 * 256;                  // 512B
    float* out   = (float*)d_out;                    // 16*256

    prep_wt3<<<dim3(1536), dim3(256), 0, stream>>>(W[0], W[1], W[8], W[9], W[16], W[17], WT);

    // word level: attn (2048 blocks, Z fused) + apply2 (512 blocks, no X pass)
    attn_kernel<1, int><<<dim3(2048), dim3(512), 0, stream>>>(
        emb, amask, WT, W[4], W[5], nullptr, nullptr, nullptr, nullptr, zbuf, cnt);
    apply2<<<dim3(512), dim3(512), 0, stream>>>(
        zbuf, cnt, W[2], W[3], W[6], W[7], sent, smask);

    // sentence level: 128 seqs of 16 -> 32 packed blocks (apply fused)
    attn_kernel<4, float><<<dim3(32), dim3(512), 0, stream>>>(
        sent, smask, WT + 512 * 256, W[12], W[13], W[10], W[11], W[14], W[15], sec, cmask);

    // section level: 16 seqs of 8 -> 2 packed blocks (apply fused)
    attn_kernel<8, float><<<dim3(2), dim3(512), 0, stream>>>(
        sec, cmask, WT + 2 * 512 * 256, W[20], W[21], W[18], W[19], W[22], W[23], out, nullptr);
}

// Round 6
// 176.501 us; speedup vs baseline: 5.0319x; 1.0388x over previous
//
#include <hip/hip_runtime.h>

constexpr int D = 256;

typedef __attribute__((ext_vector_type(8))) __bf16 bf16x8;
typedef __attribute__((ext_vector_type(4))) float f32x4;

__device__ inline unsigned short f2b(float f) {
    unsigned u = __builtin_bit_cast(unsigned, f);
    u = (u + 0x7fffu + ((u >> 16) & 1u)) >> 16;   // RNE
    return (unsigned short)u;
}
__device__ inline unsigned cvt_pk_bf16(float lo, float hi) {
    unsigned r;
    asm volatile("v_cvt_pk_bf16_f32 %0, %1, %2" : "=v"(r) : "v"(lo), "v"(hi));
    return r;
}
__device__ inline bf16x8 ld_frag(const void* p) {
    uint4 r = *(const uint4*)p;
    return __builtin_bit_cast(bf16x8, r);
}
// ---- DPP row_ror rotate-reduce across each 16-lane row (pure VALU, no LDS pipe) ----
template<int CTRL>
__device__ inline float dpp_f(float v) {
    return __builtin_bit_cast(float,
        __builtin_amdgcn_update_dpp(0, __builtin_bit_cast(int, v), CTRL, 0xf, 0xf, true));
}
__device__ inline float rsum16(float v) {
    v += dpp_f<0x121>(v);   // row_ror:1
    v += dpp_f<0x122>(v);   // row_ror:2
    v += dpp_f<0x124>(v);   // row_ror:4
    v += dpp_f<0x128>(v);   // row_ror:8
    return v;
}
__device__ inline float rmax16(float v) {
    v = fmaxf(v, dpp_f<0x121>(v));
    v = fmaxf(v, dpp_f<0x122>(v));
    v = fmaxf(v, dpp_f<0x124>(v));
    v = fmaxf(v, dpp_f<0x128>(v));
    return v;
}

// ---- prep (all 3 levels): WT[lvl][c][k] = bf16( c<256 ? Wq[k][c] : Wk[k][c-256] ) ----
__global__ void prep_wt3(const float* __restrict__ q0, const float* __restrict__ k0,
                         const float* __restrict__ q1, const float* __restrict__ k1,
                         const float* __restrict__ q2, const float* __restrict__ k2,
                         unsigned short* __restrict__ WT) {
    const int b = blockIdx.x, k = threadIdx.x;
    const int lvl = b >> 9, c = b & 511;
    const float* Wq = (lvl == 0) ? q0 : (lvl == 1) ? q1 : q2;
    const float* Wk = (lvl == 0) ? k0 : (lvl == 1) ? k1 : k2;
    const float* W = (c < 256) ? Wq : Wk;
    WT[(size_t)b * 256 + k] = f2b(W[k * 256 + (c & 255)]);
}

// ================== unified attention kernel: 64 packed tokens / block ==================
// NSUB sub-seqs of LSUB=64/NSUB tokens. NSUB==1 (word): computes Z[blk][4][256] = abar@X
// from the held bf16-X registers (no second X pass) + Cnt. NSUB>1: full apply fused.
template<int NSUB, typename MT>
__global__ __launch_bounds__(512, 4)
void attn_kernel(const float* __restrict__ X, const MT* __restrict__ Mask,
                 const unsigned short* __restrict__ WT,
                 const float* __restrict__ bq, const float* __restrict__ bk,
                 const float* __restrict__ Wv, const float* __restrict__ Wo,
                 const float* __restrict__ bv, const float* __restrict__ bo,
                 float* __restrict__ Out0, float* __restrict__ Out1)
{
    constexpr int LSUB = 64 / NSUB;
    constexpr int L2S  = (LSUB == 64) ? 6 : (LSUB == 16) ? 4 : 3;
    constexpr int NS   = (NSUB > 1) ? NSUB : 1;

    __shared__ unsigned short sQK[64 * 512];  // 64KB: bf16 X -> bf16 Q|K -> fp32 z partials
    __shared__ float sM[64];
    __shared__ float sPart[8][64];
    __shared__ float sCt[NS];
    __shared__ float sAbar[4][64];            // head-major (conflict-free write + bcast read)
    __shared__ float sPP[NS][256];
    __shared__ float sH[2][NS][256];

    const int tid = threadIdx.x;
    const int blk = blockIdx.x;
    const float* Xs = X + (size_t)blk * 64 * D;
    char* sB = (char*)sQK;
    const int lane = tid & 63, w = tid >> 6;
    const int lr = lane & 15, lg = lane >> 4;

    // ---- stage X -> bf16 LDS [64][256], pitch 512B, swizzle ((row&7)<<4); keep pk in regs ----
    uint2 pk[8];
    {
        const float4* X4 = (const float4*)Xs;
        float4 xv[8];
        #pragma unroll
        for (int j = 0; j < 8; ++j) xv[j] = X4[tid + j * 512];
        if (tid < 64) sM[tid] = (float)Mask[(size_t)blk * 64 + tid];
        #pragma unroll
        for (int j = 0; j < 8; ++j) {
            pk[j].x = cvt_pk_bf16(xv[j].x, xv[j].y);
            pk[j].y = cvt_pk_bf16(xv[j].z, xv[j].w);
            const int row = w + 8 * j;      // == (tid + j*512) >> 6
            *(uint2*)(sB + row * 512 + ((lane * 8) ^ ((row & 7) << 4))) = pk[j];
        }
    }
    __syncthreads();
    // ---- per-subseq counts: wave-parallel segmented reduce ----
    if (tid < 64) {
        float v = sM[tid];
        #pragma unroll
        for (int o = 1; o < LSUB; o <<= 1) v += __shfl_xor(v, o);
        if ((tid & (LSUB - 1)) == 0) sCt[tid >> L2S] = v;
    }

    // ---- proj': C[feature][token]; wave w owns features w*64..+63 (Q: w<4, K: w>=4) ----
    f32x4 acc[4][4];
    {
        const float* bias = (w < 4) ? bq : bk;
        const int fb = (w & 3) * 64;
        #pragma unroll
        for (int m = 0; m < 4; ++m) {
            float4 b4 = *(const float4*)(bias + fb + m * 16 + lg * 4);
            f32x4 bi = {b4.x, b4.y, b4.z, b4.w};
            #pragma unroll
            for (int n = 0; n < 4; ++n) acc[m][n] = bi;
        }
        const unsigned short* wtp = WT + (size_t)(w * 64 + lr) * 256 + lg * 8;
        bf16x8 afn[4];
        #pragma unroll
        for (int m = 0; m < 4; ++m) afn[m] = ld_frag(wtp + m * 16 * 256);
        #pragma unroll 1
        for (int kk = 0; kk < 8; ++kk) {
            bf16x8 af[4];
            #pragma unroll
            for (int m = 0; m < 4; ++m) af[m] = afn[m];
            if (kk < 7) {
                #pragma unroll
                for (int m = 0; m < 4; ++m) afn[m] = ld_frag(wtp + m * 16 * 256 + (kk + 1) * 32);
            }
            bf16x8 bx[4];
            #pragma unroll
            for (int n = 0; n < 4; ++n) {
                int t = n * 16 + lr;
                bx[n] = ld_frag(sB + t * 512 + ((kk * 64 + lg * 16) ^ ((t & 7) << 4)));
            }
            __builtin_amdgcn_s_setprio(1);
            #pragma unroll
            for (int m = 0; m < 4; ++m)
                #pragma unroll
                for (int n = 0; n < 4; ++n)
                    acc[m][n] = __builtin_amdgcn_mfma_f32_16x16x32_bf16(af[m], bx[n], acc[m][n], 0, 0, 0);
            __builtin_amdgcn_s_setprio(0);
        }
    }
    __syncthreads();   // all X reads done before overwrite
    // ---- writeback token-major Q|K bf16 [64][512], pitch 1024B, swizzled ----
    #pragma unroll
    for (int n = 0; n < 4; ++n) {
        int t = n * 16 + lr;
        char* rowp = sB + t * 1024;
        int sw = (t & 7) << 4;
        #pragma unroll
        for (int m = 0; m < 4; ++m) {
            uint2 qk;
            qk.x = cvt_pk_bf16(acc[m][n][0], acc[m][n][1]);
            qk.y = cvt_pk_bf16(acc[m][n][2], acc[m][n][3]);
            *(uint2*)(rowp + ((w * 128 + m * 32 + lg * 8) ^ sw)) = qk;
        }
    }
    __syncthreads();

    // ---- scores + softmax + abar; h = w>>1, query rows msel*32..+31 ----
    {
        const int h = w >> 1, msel = w & 1;
        f32x4 sacc[2][4];
        #pragma unroll
        for (int m = 0; m < 2; ++m)
            #pragma unroll
            for (int n = 0; n < 4; ++n) sacc[m][n] = (f32x4){0.f, 0.f, 0.f, 0.f};
        #pragma unroll
        for (int kk = 0; kk < 2; ++kk) {
            bf16x8 qf[2];
            #pragma unroll
            for (int m = 0; m < 2; ++m) {
                int t = msel * 32 + m * 16 + lr;
                qf[m] = ld_frag(sB + t * 1024 + ((h * 128 + kk * 64 + lg * 16) ^ ((t & 7) << 4)));
            }
            __builtin_amdgcn_s_setprio(1);
            #pragma unroll
            for (int n = 0; n < 4; ++n) {
                int t = n * 16 + lr;
                bf16x8 kf = ld_frag(sB + t * 1024 + ((512 + h * 128 + kk * 64 + lg * 16) ^ ((t & 7) << 4)));
                #pragma unroll
                for (int m = 0; m < 2; ++m)
                    sacc[m][n] = __builtin_amdgcn_mfma_f32_16x16x32_bf16(qf[m], kf, sacc[m][n], 0, 0, 0);
            }
            __builtin_amdgcn_s_setprio(0);
        }
        float mcol[4];
        int csub[4];
        #pragma unroll
        for (int n = 0; n < 4; ++n) {
            mcol[n] = sM[n * 16 + lr];
            csub[n] = (n * 16 + lr) >> L2S;
        }
        constexpr float CE = 0.125f * 1.44269504f;   // fold 1/sqrt(dh) into exp2
        float pm[4] = {0.f, 0.f, 0.f, 0.f};
        #pragma unroll
        for (int m = 0; m < 2; ++m)
            #pragma unroll
            for (int r = 0; r < 4; ++r) {
                const int rowtok = msel * 32 + m * 16 + lg * 4 + r;
                const int rsub = rowtok >> L2S;
                float s[4], mx = -3.4e38f;
                #pragma unroll
                for (int n = 0; n < 4; ++n) {
                    float v = sacc[m][n][r];
                    bool ok = (mcol[n] > 0.f);
                    if constexpr (NSUB > 1) ok = ok && (csub[n] == rsub);
                    v = ok ? v : -1e9f;
                    s[n] = v; mx = fmaxf(mx, v);
                }
                mx = rmax16(mx);                       // DPP, no LDS pipe
                float e[4], se;
                #pragma unroll
                for (int n = 0; n < 4; ++n) e[n] = __builtin_amdgcn_exp2f((s[n] - mx) * CE);
                se = rsum16(((e[0] + e[1]) + (e[2] + e[3])));  // DPP
                const float wr = sM[rowtok] * __builtin_amdgcn_rcpf(se);
                #pragma unroll
                for (int n = 0; n < 4; ++n) pm[n] += e[n] * wr;
            }
        #pragma unroll
        for (int o = 16; o < 64; o <<= 1)
            #pragma unroll
            for (int n = 0; n < 4; ++n) pm[n] += __shfl_xor(pm[n], o);
        if (lane < 16)
            #pragma unroll
            for (int n = 0; n < 4; ++n) sPart[w][n * 16 + lane] = pm[n];
    }
    __syncthreads();
    // ---- abar head-major (conflict-free: consecutive tids -> consecutive dwords) ----
    if (tid < 256) {
        int h = tid >> 6, j = tid & 63;
        sAbar[h][j] = sPart[2 * h][j] + sPart[2 * h + 1][j];
    }
    __syncthreads();

    if constexpr (NSUB == 1) {
        // ---- per-thread z partials from held bf16-X regs: tokens w+8j, feats lane*4..+3 ----
        float zp[4][4];
        #pragma unroll
        for (int h = 0; h < 4; ++h)
            #pragma unroll
            for (int e = 0; e < 4; ++e) zp[h][e] = 0.f;
        #pragma unroll
        for (int j = 0; j < 8; ++j) {
            const int t = w + 8 * j;
            float ab0 = sAbar[0][t], ab1 = sAbar[1][t];   // uniform addr: broadcast
            float ab2 = sAbar[2][t], ab3 = sAbar[3][t];
            float x0 = __builtin_bit_cast(float, pk[j].x << 16);
            float x1 = __builtin_bit_cast(float, pk[j].x & 0xffff0000u);
            float x2 = __builtin_bit_cast(float, pk[j].y << 16);
            float x3 = __builtin_bit_cast(float, pk[j].y & 0xffff0000u);
            zp[0][0] = fmaf(ab0, x0, zp[0][0]); zp[0][1] = fmaf(ab0, x1, zp[0][1]);
            zp[0][2] = fmaf(ab0, x2, zp[0][2]); zp[0][3] = fmaf(ab0, x3, zp[0][3]);
            zp[1][0] = fmaf(ab1, x0, zp[1][0]); zp[1][1] = fmaf(ab1, x1, zp[1][1]);
            zp[1][2] = fmaf(ab1, x2, zp[1][2]); zp[1][3] = fmaf(ab1, x3, zp[1][3]);
            zp[2][0] = fmaf(ab2, x0, zp[2][0]); zp[2][1] = fmaf(ab2, x1, zp[2][1]);
            zp[2][2] = fmaf(ab2, x2, zp[2][2]); zp[2][3] = fmaf(ab2, x3, zp[2][3]);
            zp[3][0] = fmaf(ab3, x0, zp[3][0]); zp[3][1] = fmaf(ab3, x1, zp[3][1]);
            zp[3][2] = fmaf(ab3, x2, zp[3][2]); zp[3][3] = fmaf(ab3, x3, zp[3][3]);
        }
        // ---- cross-wave reduce via [wave][head][256] regions: b128 at lane*16 = conflict-free ----
        float* zr = (float*)sB;
        #pragma unroll
        for (int h = 0; h < 4; ++h)
            *(f32x4*)&zr[(w * 4 + h) * 256 + lane * 4] =
                (f32x4){zp[h][0], zp[h][1], zp[h][2], zp[h][3]};
        __syncthreads();
        {
            const int d = tid & 255, hp = (tid >> 8) * 2;
            float a0 = 0.f, a1 = 0.f;
            #pragma unroll
            for (int ww = 0; ww < 8; ++ww) {           // dword-stride-1 reads: conflict-free
                a0 += zr[(ww * 4 + hp) * 256 + d];
                a1 += zr[(ww * 4 + hp + 1) * 256 + d];
            }
            float* Zo = Out0 + (size_t)blk * 1024;
            Zo[hp * 256 + d] = a0;
            Zo[(hp + 1) * 256 + d] = a1;
        }
        if (tid == 0) Out1[blk] = sCt[0];
    } else {
        // ---- z partials (fp32 X from global, L2-resident) into sQK reused as float ----
        float* zpf = (float*)sB;    // [2][NSUB][4][256]
        const int d = tid & 255, rh = tid >> 8;
        constexpr int HT = LSUB / 2;
        #pragma unroll
        for (int s = 0; s < NSUB; ++s) {
            float zz[4] = {0.f, 0.f, 0.f, 0.f};
            const int t0 = s * LSUB + rh * HT;
            #pragma unroll
            for (int t = 0; t < HT; ++t) {
                float xv = Xs[(size_t)(t0 + t) * 256 + d];
                #pragma unroll
                for (int h = 0; h < 4; ++h) zz[h] = fmaf(sAbar[h][t0 + t], xv, zz[h]);
            }
            #pragma unroll
            for (int h = 0; h < 4; ++h) zpf[((rh * NSUB + s) * 4 + h) * 256 + d] = zz[h];
        }
        __syncthreads();
        // ---- pp = z @ Wv + cnt*bv ----
        {
            const int n = tid & 255, g = tid >> 8, h = n >> 6;
            float pa[NSUB];
            #pragma unroll
            for (int s = 0; s < NSUB; ++s) pa[s] = 0.f;
            for (int dc = 0; dc < 128; dc += 8) {
                float wv[8];
                #pragma unroll
                for (int q = 0; q < 8; ++q) wv[q] = Wv[(size_t)(g * 128 + dc + q) * 256 + n];
                #pragma unroll
                for (int s = 0; s < NSUB; ++s)
                    #pragma unroll
                    for (int q = 0; q < 8; ++q) {
                        int dd = g * 128 + dc + q;
                        float zv = zpf[(s * 4 + h) * 256 + dd] + zpf[((NSUB + s) * 4 + h) * 256 + dd];
                        pa[s] = fmaf(zv, wv[q], pa[s]);
                    }
            }
            #pragma unroll
            for (int s = 0; s < NSUB; ++s) sH[g][s][n] = pa[s];
        }
        __syncthreads();
        for (int i = tid; i < NSUB * 256; i += 512) {
            int s = i >> 8, nn = i & 255;
            sPP[s][nn] = sH[0][s][nn] + sH[1][s][nn] + sCt[s] * bv[nn];
        }
        __syncthreads();
        // ---- out = pp @ Wo / cnt + bo ----
        {
            const int n = tid & 255, g = tid >> 8;
            float pa[NSUB];
            #pragma unroll
            for (int s = 0; s < NSUB; ++s) pa[s] = 0.f;
            for (int dc = 0; dc < 128; dc += 8) {
                float wo[8];
                #pragma unroll
                for (int q = 0; q < 8; ++q) wo[q] = Wo[(size_t)(g * 128 + dc + q) * 256 + n];
                #pragma unroll
                for (int s = 0; s < NSUB; ++s) {
                    const float* pp = &sPP[s][g * 128 + dc];
                    #pragma unroll
                    for (int q = 0; q < 8; ++q) pa[s] = fmaf(pp[q], wo[q], pa[s]);
                }
            }
            #pragma unroll
            for (int s = 0; s < NSUB; ++s) sH[g][s][n] = pa[s];
        }
        __syncthreads();
        for (int i = tid; i < NSUB * 256; i += 512) {
            int s = i >> 8, nn = i & 255;
            float c = sCt[s];
            Out0[(size_t)(blk * NSUB + s) * 256 + nn] =
                (c > 0.f) ? ((sH[0][s][nn] + sH[1][s][nn]) / c + bo[nn]) : 0.f;
        }
        if (tid < NSUB && Out1) Out1[blk * NSUB + tid] = (sCt[tid] > 0.f) ? 1.f : 0.f;
    }
}

// =============== apply2: pp = Z@Wv + cnt*bv ; out = pp@Wo/cnt + bo  (no X pass) ===============
__global__ __launch_bounds__(512, 2)
void apply2(const float* __restrict__ Z, const float* __restrict__ Cnt,
            const float* __restrict__ Wv, const float* __restrict__ Wo,
            const float* __restrict__ bv, const float* __restrict__ bo,
            float* __restrict__ Out, float* __restrict__ MaskOut)
{
    constexpr int SPB = 8;
    __shared__ float sZ[SPB][4][256];   // 32KB
    __shared__ float sPP[SPB][256];     // 8KB
    __shared__ float sH[2][SPB][256];   // 16KB
    __shared__ float sCt[SPB];

    const int tid = threadIdx.x;
    const int s0 = blockIdx.x * SPB;
    {
        const float4* Zf = (const float4*)(Z + (size_t)s0 * 1024);
        float4* sZf = (float4*)sZ;
        #pragma unroll
        for (int k = 0; k < 4; ++k) sZf[tid + k * 512] = Zf[tid + k * 512];
        if (tid < SPB) sCt[tid] = Cnt[s0 + tid];
    }
    __syncthreads();

    const int n = tid & 255, g = tid >> 8, h = n >> 6;

    {
        float pa[SPB] = {};
        for (int dc = 0; dc < 128; dc += 16) {
            float wv[16];
            #pragma unroll
            for (int q = 0; q < 16; ++q) wv[q] = Wv[(size_t)(g * 128 + dc + q) * 256 + n];
            #pragma unroll
            for (int s = 0; s < SPB; ++s) {
                const float4* zp4 = (const float4*)&sZ[s][h][g * 128 + dc];
                #pragma unroll
                for (int q4 = 0; q4 < 4; ++q4) {
                    float4 zv = zp4[q4];
                    pa[s] = fmaf(zv.x, wv[q4 * 4 + 0], pa[s]);
                    pa[s] = fmaf(zv.y, wv[q4 * 4 + 1], pa[s]);
                    pa[s] = fmaf(zv.z, wv[q4 * 4 + 2], pa[s]);
                    pa[s] = fmaf(zv.w, wv[q4 * 4 + 3], pa[s]);
                }
            }
        }
        #pragma unroll
        for (int s = 0; s < SPB; ++s) sH[g][s][n] = pa[s];
    }
    __syncthreads();
    for (int i = tid; i < SPB * 256; i += 512) {
        int s = i >> 8, nn = i & 255;
        sPP[s][nn] = sH[0][s][nn] + sH[1][s][nn] + sCt[s] * bv[nn];
    }
    __syncthreads();
    {
        float pa[SPB] = {};
        for (int dc = 0; dc < 128; dc += 16) {
            float wo[16];
            #pragma unroll
            for (int q = 0; q < 16; ++q) wo[q] = Wo[(size_t)(g * 128 + dc + q) * 256 + n];
            #pragma unroll
            for (int s = 0; s < SPB; ++s) {
                const float4* pp = (const float4*)&sPP[s][g * 128 + dc];
                #pragma unroll
                for (int q4 = 0; q4 < 4; ++q4) {
                    float4 pv = pp[q4];
                    pa[s] = fmaf(pv.x, wo[q4 * 4 + 0], pa[s]);
                    pa[s] = fmaf(pv.y, wo[q4 * 4 + 1], pa[s]);
                    pa[s] = fmaf(pv.z, wo[q4 * 4 + 2], pa[s]);
                    pa[s] = fmaf(pv.w, wo[q4 * 4 + 3], pa[s]);
                }
            }
        }
        #pragma unroll
        for (int s = 0; s < SPB; ++s) sH[g][s][n] = pa[s];
    }
    __syncthreads();
    for (int i = tid; i < SPB * 256; i += 512) {
        int s = i >> 8, nn = i & 255;
        float c = sCt[s];
        Out[(size_t)(s0 + s) * 256 + nn] = (c > 0.f) ? ((sH[0][s][nn] + sH[1][s][nn]) / c + bo[nn]) : 0.f;
    }
    if (tid < SPB && MaskOut) MaskOut[s0 + tid] = (sCt[tid] > 0.f) ? 1.f : 0.f;
}

extern "C" void kernel_launch(void* const* d_in, const int* in_sizes, int n_in,
                              void* d_out, int out_size, void* d_ws, size_t ws_size,
                              hipStream_t stream)
{
    const float* emb  = (const float*)d_in[0];
    const int*  amask = (const int*)d_in[1];
    const float* W[24];
    for (int i = 0; i < 24; ++i) W[i] = (const float*)d_in[2 + i];
    // W[0..7] = wWq,wWk,wWv,wWo,wbq,wbk,wbv,wbo ; W[8..15] = s* ; W[16..23] = c*

    char* ws = (char*)d_ws;
    unsigned short* WT = (unsigned short*)ws;        // 3 * 512*256 * 2B = 768KB
    float* zbuf  = (float*)(ws + 3 * 256 * 1024);    // 2048*4*256 = 8MB
    float* cnt   = zbuf + 2048 * 1024;               // 8KB
    float* sent  = cnt + 2048;                       // 2MB
    float* smask = sent + 2048 * 256;                // 8KB
    float* sec   = smask + 2048;                     // 128KB
    float* cmask = sec + 128 * 256;                  // 512B
    float* out   = (float*)d_out;                    // 16*256

    prep_wt3<<<dim3(1536), dim3(256), 0, stream>>>(W[0], W[1], W[8], W[9], W[16], W[17], WT);

    // word level: attn (2048 blocks, Z fused) + apply2 (256 blocks, no X pass)
    attn_kernel<1, int><<<dim3(2048), dim3(512), 0, stream>>>(
        emb, amask, WT, W[4], W[5], nullptr, nullptr, nullptr, nullptr, zbuf, cnt);
    apply2<<<dim3(256), dim3(512), 0, stream>>>(
        zbuf, cnt, W[2], W[3], W[6], W[7], sent, smask);

    // sentence level: 128 seqs of 16 -> 32 packed blocks (apply fused)
    attn_kernel<4, float><<<dim3(32), dim3(512), 0, stream>>>(
        sent, smask, WT + 512 * 256, W[12], W[13], W[10], W[11], W[14], W[15], sec, cmask);

    // section level: 16 seqs of 8 -> 2 packed blocks (apply fused)
    attn_kernel<8, float><<<dim3(2), dim3(512), 0, stream>>>(
        sec, cmask, WT + 2 * 512 * 256, W[20], W[21], W[18], W[19], W[22], W[23], out, nullptr);
}

// Round 7
// 151.626 us; speedup vs baseline: 5.8574x; 1.1641x over previous
//
#include <hip/hip_runtime.h>

constexpr int D = 256;

typedef __attribute__((ext_vector_type(8))) __bf16 bf16x8;
typedef __attribute__((ext_vector_type(4))) float f32x4;

__device__ inline unsigned short f2b(float f) {
    unsigned u = __builtin_bit_cast(unsigned, f);
    u = (u + 0x7fffu + ((u >> 16) & 1u)) >> 16;   // RNE
    return (unsigned short)u;
}
__device__ inline unsigned cvt_pk_bf16(float lo, float hi) {
    unsigned r;
    asm volatile("v_cvt_pk_bf16_f32 %0, %1, %2" : "=v"(r) : "v"(lo), "v"(hi));
    return r;
}
__device__ inline bf16x8 ld_frag(const void* p) {
    uint4 r = *(const uint4*)p;
    return __builtin_bit_cast(bf16x8, r);
}
// ---- DPP row_ror rotate-reduce across each 16-lane row (pure VALU, no LDS pipe) ----
template<int CTRL>
__device__ inline float dpp_f(float v) {
    return __builtin_bit_cast(float,
        __builtin_amdgcn_update_dpp(0, __builtin_bit_cast(int, v), CTRL, 0xf, 0xf, true));
}
__device__ inline float rsum16(float v) {
    v += dpp_f<0x121>(v);
    v += dpp_f<0x122>(v);
    v += dpp_f<0x124>(v);
    v += dpp_f<0x128>(v);
    return v;
}
__device__ inline float rmax16(float v) {
    v = fmaxf(v, dpp_f<0x121>(v));
    v = fmaxf(v, dpp_f<0x122>(v));
    v = fmaxf(v, dpp_f<0x124>(v));
    v = fmaxf(v, dpp_f<0x128>(v));
    return v;
}
constexpr float CE = 0.125f * 1.44269504f;   // 1/sqrt(dh) folded into exp2

// ---- prep (all 3 levels): WT[lvl][c][k] = bf16( c<256 ? Wq[k][c] : Wk[k][c-256] ) ----
__global__ void prep_wt3(const float* __restrict__ q0, const float* __restrict__ k0,
                         const float* __restrict__ q1, const float* __restrict__ k1,
                         const float* __restrict__ q2, const float* __restrict__ k2,
                         unsigned short* __restrict__ WT) {
    const int b = blockIdx.x, k = threadIdx.x;
    const int lvl = b >> 9, c = b & 511;
    const float* Wq = (lvl == 0) ? q0 : (lvl == 1) ? q1 : q2;
    const float* Wk = (lvl == 0) ? k0 : (lvl == 1) ? k1 : k2;
    const float* W = (c < 256) ? Wq : Wk;
    WT[(size_t)b * 256 + k] = f2b(W[k * 256 + (c & 255)]);
}

// ================== word level K1: 64 tokens / block -> Z[blk][4][256], Cnt ==================
__global__ __launch_bounds__(512, 4)
void word_attn(const float* __restrict__ X, const int* __restrict__ Mask,
               const unsigned short* __restrict__ WT,
               const float* __restrict__ bq, const float* __restrict__ bk,
               float* __restrict__ Zout, float* __restrict__ Cnt)
{
    __shared__ unsigned short sQK[64 * 512];  // 64KB: bf16 X -> bf16 Q|K -> fp32 z partials
    __shared__ float sM[64];
    __shared__ float sPart[8][64];
    __shared__ float sAbar[4][64];
    __shared__ float sCt;

    const int tid = threadIdx.x;
    const int blk = blockIdx.x;
    const float* Xs = X + (size_t)blk * 64 * D;
    char* sB = (char*)sQK;
    const int lane = tid & 63, w = tid >> 6;
    const int lr = lane & 15, lg = lane >> 4;

    // ---- stage X -> bf16 LDS [64][256], pitch 512B, swizzle ((row&7)<<4); keep pk in regs ----
    uint2 pk[8];
    {
        const float4* X4 = (const float4*)Xs;
        float4 xv[8];
        #pragma unroll
        for (int j = 0; j < 8; ++j) xv[j] = X4[tid + j * 512];
        if (tid < 64) sM[tid] = (float)Mask[(size_t)blk * 64 + tid];
        #pragma unroll
        for (int j = 0; j < 8; ++j) {
            pk[j].x = cvt_pk_bf16(xv[j].x, xv[j].y);
            pk[j].y = cvt_pk_bf16(xv[j].z, xv[j].w);
            const int row = w + 8 * j;
            *(uint2*)(sB + row * 512 + ((lane * 8) ^ ((row & 7) << 4))) = pk[j];
        }
    }
    // pre-issue first WT fragments (L2) so their latency hides under the barrier drain
    const unsigned short* wtp = WT + (size_t)(w * 64 + lr) * 256 + lg * 8;
    bf16x8 afn[4];
    #pragma unroll
    for (int m = 0; m < 4; ++m) afn[m] = ld_frag(wtp + m * 16 * 256);
    __syncthreads();
    if (tid < 64) {
        float v = sM[tid];
        #pragma unroll
        for (int o = 1; o < 64; o <<= 1) v += __shfl_xor(v, o);
        if (tid == 0) sCt = v;
    }

    // ---- proj': C[feature][token]; wave w owns features w*64..+63 (Q: w<4, K: w>=4) ----
    f32x4 acc[4][4];
    {
        const float* bias = (w < 4) ? bq : bk;
        const int fb = (w & 3) * 64;
        #pragma unroll
        for (int m = 0; m < 4; ++m) {
            float4 b4 = *(const float4*)(bias + fb + m * 16 + lg * 4);
            f32x4 bi = {b4.x, b4.y, b4.z, b4.w};
            #pragma unroll
            for (int n = 0; n < 4; ++n) acc[m][n] = bi;
        }
        #pragma unroll 1
        for (int kk = 0; kk < 8; ++kk) {
            bf16x8 af[4];
            #pragma unroll
            for (int m = 0; m < 4; ++m) af[m] = afn[m];
            if (kk < 7) {
                #pragma unroll
                for (int m = 0; m < 4; ++m) afn[m] = ld_frag(wtp + m * 16 * 256 + (kk + 1) * 32);
            }
            bf16x8 bx[4];
            #pragma unroll
            for (int n = 0; n < 4; ++n) {
                int t = n * 16 + lr;
                bx[n] = ld_frag(sB + t * 512 + ((kk * 64 + lg * 16) ^ ((t & 7) << 4)));
            }
            __builtin_amdgcn_s_setprio(1);
            #pragma unroll
            for (int m = 0; m < 4; ++m)
                #pragma unroll
                for (int n = 0; n < 4; ++n)
                    acc[m][n] = __builtin_amdgcn_mfma_f32_16x16x32_bf16(af[m], bx[n], acc[m][n], 0, 0, 0);
            __builtin_amdgcn_s_setprio(0);
        }
    }
    __syncthreads();   // all X reads done before overwrite
    // ---- writeback token-major Q|K bf16 [64][512], pitch 1024B, swizzled ----
    #pragma unroll
    for (int n = 0; n < 4; ++n) {
        int t = n * 16 + lr;
        char* rowp = sB + t * 1024;
        int sw = (t & 7) << 4;
        #pragma unroll
        for (int m = 0; m < 4; ++m) {
            uint2 qk;
            qk.x = cvt_pk_bf16(acc[m][n][0], acc[m][n][1]);
            qk.y = cvt_pk_bf16(acc[m][n][2], acc[m][n][3]);
            *(uint2*)(rowp + ((w * 128 + m * 32 + lg * 8) ^ sw)) = qk;
        }
    }
    __syncthreads();

    // ---- scores + softmax + abar; h = w>>1, query rows msel*32..+31 ----
    {
        const int h = w >> 1, msel = w & 1;
        f32x4 sacc[2][4];
        #pragma unroll
        for (int m = 0; m < 2; ++m)
            #pragma unroll
            for (int n = 0; n < 4; ++n) sacc[m][n] = (f32x4){0.f, 0.f, 0.f, 0.f};
        #pragma unroll
        for (int kk = 0; kk < 2; ++kk) {
            bf16x8 qf[2];
            #pragma unroll
            for (int m = 0; m < 2; ++m) {
                int t = msel * 32 + m * 16 + lr;
                qf[m] = ld_frag(sB + t * 1024 + ((h * 128 + kk * 64 + lg * 16) ^ ((t & 7) << 4)));
            }
            __builtin_amdgcn_s_setprio(1);
            #pragma unroll
            for (int n = 0; n < 4; ++n) {
                int t = n * 16 + lr;
                bf16x8 kf = ld_frag(sB + t * 1024 + ((512 + h * 128 + kk * 64 + lg * 16) ^ ((t & 7) << 4)));
                #pragma unroll
                for (int m = 0; m < 2; ++m)
                    sacc[m][n] = __builtin_amdgcn_mfma_f32_16x16x32_bf16(qf[m], kf, sacc[m][n], 0, 0, 0);
            }
            __builtin_amdgcn_s_setprio(0);
        }
        float mcol[4];
        #pragma unroll
        for (int n = 0; n < 4; ++n) mcol[n] = sM[n * 16 + lr];
        float pm[4] = {0.f, 0.f, 0.f, 0.f};
        #pragma unroll
        for (int m = 0; m < 2; ++m)
            #pragma unroll
            for (int r = 0; r < 4; ++r) {
                const int rowtok = msel * 32 + m * 16 + lg * 4 + r;
                float s[4], mx = -3.4e38f;
                #pragma unroll
                for (int n = 0; n < 4; ++n) {
                    float v = sacc[m][n][r];
                    v = (mcol[n] > 0.f) ? v : -1e9f;
                    s[n] = v; mx = fmaxf(mx, v);
                }
                mx = rmax16(mx);
                float e[4], se;
                #pragma unroll
                for (int n = 0; n < 4; ++n) e[n] = __builtin_amdgcn_exp2f((s[n] - mx) * CE);
                se = rsum16(((e[0] + e[1]) + (e[2] + e[3])));
                const float wr = sM[rowtok] * __builtin_amdgcn_rcpf(se);
                #pragma unroll
                for (int n = 0; n < 4; ++n) pm[n] += e[n] * wr;
            }
        #pragma unroll
        for (int o = 16; o < 64; o <<= 1)
            #pragma unroll
            for (int n = 0; n < 4; ++n) pm[n] += __shfl_xor(pm[n], o);
        if (lane < 16)
            #pragma unroll
            for (int n = 0; n < 4; ++n) sPart[w][n * 16 + lane] = pm[n];
    }
    __syncthreads();
    if (tid < 256) {
        int h = tid >> 6, j = tid & 63;
        sAbar[h][j] = sPart[2 * h][j] + sPart[2 * h + 1][j];
    }
    __syncthreads();

    // ---- z from held bf16-X regs: tokens w+8j, feats lane*4..+3 ----
    float zp[4][4];
    #pragma unroll
    for (int h = 0; h < 4; ++h)
        #pragma unroll
        for (int e = 0; e < 4; ++e) zp[h][e] = 0.f;
    #pragma unroll
    for (int j = 0; j < 8; ++j) {
        const int t = w + 8 * j;
        float ab0 = sAbar[0][t], ab1 = sAbar[1][t];
        float ab2 = sAbar[2][t], ab3 = sAbar[3][t];
        float x0 = __builtin_bit_cast(float, pk[j].x << 16);
        float x1 = __builtin_bit_cast(float, pk[j].x & 0xffff0000u);
        float x2 = __builtin_bit_cast(float, pk[j].y << 16);
        float x3 = __builtin_bit_cast(float, pk[j].y & 0xffff0000u);
        zp[0][0] = fmaf(ab0, x0, zp[0][0]); zp[0][1] = fmaf(ab0, x1, zp[0][1]);
        zp[0][2] = fmaf(ab0, x2, zp[0][2]); zp[0][3] = fmaf(ab0, x3, zp[0][3]);
        zp[1][0] = fmaf(ab1, x0, zp[1][0]); zp[1][1] = fmaf(ab1, x1, zp[1][1]);
        zp[1][2] = fmaf(ab1, x2, zp[1][2]); zp[1][3] = fmaf(ab1, x3, zp[1][3]);
        zp[2][0] = fmaf(ab2, x0, zp[2][0]); zp[2][1] = fmaf(ab2, x1, zp[2][1]);
        zp[2][2] = fmaf(ab2, x2, zp[2][2]); zp[2][3] = fmaf(ab2, x3, zp[2][3]);
        zp[3][0] = fmaf(ab3, x0, zp[3][0]); zp[3][1] = fmaf(ab3, x1, zp[3][1]);
        zp[3][2] = fmaf(ab3, x2, zp[3][2]); zp[3][3] = fmaf(ab3, x3, zp[3][3]);
    }
    // ---- cross-wave reduce via [wave][head][256]: b128 at lane*16 = conflict-free ----
    float* zr = (float*)sB;
    #pragma unroll
    for (int h = 0; h < 4; ++h)
        *(f32x4*)&zr[(w * 4 + h) * 256 + lane * 4] =
            (f32x4){zp[h][0], zp[h][1], zp[h][2], zp[h][3]};
    __syncthreads();
    {
        const int d = tid & 255, hp = (tid >> 8) * 2;
        float a0 = 0.f, a1 = 0.f;
        #pragma unroll
        for (int ww = 0; ww < 8; ++ww) {
            a0 += zr[(ww * 4 + hp) * 256 + d];
            a1 += zr[(ww * 4 + hp + 1) * 256 + d];
        }
        float* Zo = Zout + (size_t)blk * 1024;
        Zo[hp * 256 + d] = a0;
        Zo[(hp + 1) * 256 + d] = a1;
    }
    if (tid == 0) Cnt[blk] = sCt;
}

// =============== apply2: pp = Z@Wv + cnt*bv ; out = pp@Wo/cnt + bo ===============
__global__ __launch_bounds__(512, 2)
void apply2(const float* __restrict__ Z, const float* __restrict__ Cnt,
            const float* __restrict__ Wv, const float* __restrict__ Wo,
            const float* __restrict__ bv, const float* __restrict__ bo,
            float* __restrict__ Out, float* __restrict__ MaskOut)
{
    constexpr int SPB = 8;
    __shared__ float sZ[SPB][4][256];
    __shared__ float sPP[SPB][256];
    __shared__ float sH[2][SPB][256];
    __shared__ float sCt[SPB];

    const int tid = threadIdx.x;
    const int s0 = blockIdx.x * SPB;
    {
        const float4* Zf = (const float4*)(Z + (size_t)s0 * 1024);
        float4* sZf = (float4*)sZ;
        #pragma unroll
        for (int k = 0; k < 4; ++k) sZf[tid + k * 512] = Zf[tid + k * 512];
        if (tid < SPB) sCt[tid] = Cnt[s0 + tid];
    }
    __syncthreads();

    const int n = tid & 255, g = tid >> 8, h = n >> 6;

    {
        float pa[SPB] = {};
        for (int dc = 0; dc < 128; dc += 16) {
            float wv[16];
            #pragma unroll
            for (int q = 0; q < 16; ++q) wv[q] = Wv[(size_t)(g * 128 + dc + q) * 256 + n];
            #pragma unroll
            for (int s = 0; s < SPB; ++s) {
                const float4* zp4 = (const float4*)&sZ[s][h][g * 128 + dc];
                #pragma unroll
                for (int q4 = 0; q4 < 4; ++q4) {
                    float4 zv = zp4[q4];
                    pa[s] = fmaf(zv.x, wv[q4 * 4 + 0], pa[s]);
                    pa[s] = fmaf(zv.y, wv[q4 * 4 + 1], pa[s]);
                    pa[s] = fmaf(zv.z, wv[q4 * 4 + 2], pa[s]);
                    pa[s] = fmaf(zv.w, wv[q4 * 4 + 3], pa[s]);
                }
            }
        }
        #pragma unroll
        for (int s = 0; s < SPB; ++s) sH[g][s][n] = pa[s];
    }
    __syncthreads();
    for (int i = tid; i < SPB * 256; i += 512) {
        int s = i >> 8, nn = i & 255;
        sPP[s][nn] = sH[0][s][nn] + sH[1][s][nn] + sCt[s] * bv[nn];
    }
    __syncthreads();
    {
        float pa[SPB] = {};
        for (int dc = 0; dc < 128; dc += 16) {
            float wo[16];
            #pragma unroll
            for (int q = 0; q < 16; ++q) wo[q] = Wo[(size_t)(g * 128 + dc + q) * 256 + n];
            #pragma unroll
            for (int s = 0; s < SPB; ++s) {
                const float4* pp = (const float4*)&sPP[s][g * 128 + dc];
                #pragma unroll
                for (int q4 = 0; q4 < 4; ++q4) {
                    float4 pv = pp[q4];
                    pa[s] = fmaf(pv.x, wo[q4 * 4 + 0], pa[s]);
                    pa[s] = fmaf(pv.y, wo[q4 * 4 + 1], pa[s]);
                    pa[s] = fmaf(pv.z, wo[q4 * 4 + 2], pa[s]);
                    pa[s] = fmaf(pv.w, wo[q4 * 4 + 3], pa[s]);
                }
            }
        }
        #pragma unroll
        for (int s = 0; s < SPB; ++s) sH[g][s][n] = pa[s];
    }
    __syncthreads();
    for (int i = tid; i < SPB * 256; i += 512) {
        int s = i >> 8, nn = i & 255;
        float c = sCt[s];
        Out[(size_t)(s0 + s) * 256 + nn] = (c > 0.f) ? ((sH[0][s][nn] + sH[1][s][nn]) / c + bo[nn]) : 0.f;
    }
    if (tid < SPB && MaskOut) MaskOut[s0 + tid] = (sCt[tid] > 0.f) ? 1.f : 0.f;
}

// ============ tail: ONE sequence (<=16 tokens, zero-padded) per block, fully fused ============
template<int LREAL>
__global__ __launch_bounds__(512, 2)
void tail_kernel(const float* __restrict__ X, const float* __restrict__ MaskIn,
                 const unsigned short* __restrict__ WT,
                 const float* __restrict__ bq, const float* __restrict__ bk,
                 const float* __restrict__ Wv, const float* __restrict__ Wo,
                 const float* __restrict__ bv, const float* __restrict__ bo,
                 float* __restrict__ Out, float* __restrict__ MaskOut)
{
    __shared__ unsigned short sX[16 * 256];   // 8KB bf16, pitch 512B, swizzled
    __shared__ unsigned short sQK[16 * 512];  // 16KB bf16, pitch 1024B, swizzled
    __shared__ float sXF[16][256];            // 16KB fp32 copy for z (exact numerics)
    __shared__ float sM[16];
    __shared__ float sAbar[4][16];
    __shared__ float sZp[2][4][256];          // 8KB
    __shared__ float sPP[256];
    __shared__ float sHH[2][256];
    __shared__ float sCt;

    const int tid = threadIdx.x;
    const int seq = blockIdx.x;
    const float* Xs = X + (size_t)seq * LREAL * 256;
    char* sBX = (char*)sX;
    char* sBQ = (char*)sQK;
    const int lane = tid & 63, w = tid >> 6;
    const int lr = lane & 15, lg = lane >> 4;

    // ---- stage (zero-pad rows >= LREAL) ----
    {
        const float4* X4 = (const float4*)Xs;
        #pragma unroll
        for (int j = 0; j < 2; ++j) {
            int idx = tid + j * 512;
            int row = idx >> 6, c4 = idx & 63;
            float4 v = (row < LREAL) ? X4[row * 64 + c4] : (float4){0.f, 0.f, 0.f, 0.f};
            uint2 p;
            p.x = cvt_pk_bf16(v.x, v.y);
            p.y = cvt_pk_bf16(v.z, v.w);
            *(uint2*)(sBX + row * 512 + ((c4 * 8) ^ ((row & 7) << 4))) = p;
            *(float4*)&sXF[row][c4 * 4] = v;
        }
        if (tid < 16) sM[tid] = (tid < LREAL) ? MaskIn[seq * LREAL + tid] : 0.f;
    }
    // pre-issue first WT fragments
    const unsigned short* wtp = WT + (size_t)(w * 64 + lr) * 256 + lg * 8;
    bf16x8 afn[4];
    #pragma unroll
    for (int m = 0; m < 4; ++m) afn[m] = ld_frag(wtp + m * 16 * 256);
    __syncthreads();
    if (tid < 64) {
        float v = (lane < LREAL) ? sM[lane] : 0.f;
        v = rsum16(v);
        if (lane == 0) sCt = v;
    }

    // ---- proj': wave w owns features w*64..+63 (Q: w<4, K: w>=4); single token tile ----
    f32x4 acc[4];
    {
        const float* bias = (w < 4) ? bq : bk;
        const int fb = (w & 3) * 64;
        #pragma unroll
        for (int m = 0; m < 4; ++m) {
            float4 b4 = *(const float4*)(bias + fb + m * 16 + lg * 4);
            acc[m] = (f32x4){b4.x, b4.y, b4.z, b4.w};
        }
        #pragma unroll 1
        for (int kk = 0; kk < 8; ++kk) {
            bf16x8 af[4];
            #pragma unroll
            for (int m = 0; m < 4; ++m) af[m] = afn[m];
            if (kk < 7) {
                #pragma unroll
                for (int m = 0; m < 4; ++m) afn[m] = ld_frag(wtp + m * 16 * 256 + (kk + 1) * 32);
            }
            bf16x8 bx = ld_frag(sBX + lr * 512 + ((kk * 64 + lg * 16) ^ ((lr & 7) << 4)));
            #pragma unroll
            for (int m = 0; m < 4; ++m)
                acc[m] = __builtin_amdgcn_mfma_f32_16x16x32_bf16(af[m], bx, acc[m], 0, 0, 0);
        }
    }
    // ---- writeback: thread holds token lr, feats w*64+m*16+lg*4+r ----
    #pragma unroll
    for (int m = 0; m < 4; ++m) {
        uint2 qk;
        qk.x = cvt_pk_bf16(acc[m][0], acc[m][1]);
        qk.y = cvt_pk_bf16(acc[m][2], acc[m][3]);
        *(uint2*)(sBQ + lr * 1024 + ((w * 128 + m * 32 + lg * 8) ^ ((lr & 7) << 4))) = qk;
    }
    __syncthreads();

    // ---- scores + softmax + abar: wave h (<4) does head h's 16x16 tile ----
    if (w < 4) {
        const int h = w;
        f32x4 sacc = (f32x4){0.f, 0.f, 0.f, 0.f};
        #pragma unroll
        for (int kk = 0; kk < 2; ++kk) {
            bf16x8 qf = ld_frag(sBQ + lr * 1024 + ((h * 128 + kk * 64 + lg * 16) ^ ((lr & 7) << 4)));
            bf16x8 kf = ld_frag(sBQ + lr * 1024 + ((512 + h * 128 + kk * 64 + lg * 16) ^ ((lr & 7) << 4)));
            sacc = __builtin_amdgcn_mfma_f32_16x16x32_bf16(qf, kf, sacc, 0, 0, 0);
        }
        const float mkey = sM[lr];
        float t = 0.f;
        #pragma unroll
        for (int r = 0; r < 4; ++r) {
            const int qi = lg * 4 + r;
            float s = (mkey > 0.f) ? sacc[r] : -1e9f;
            float mx = rmax16(s);
            float e = __builtin_amdgcn_exp2f((s - mx) * CE);
            float se = rsum16(e);
            t += e * (sM[qi] * __builtin_amdgcn_rcpf(se));   // m_qi * a[qi][lr]
        }
        t += __shfl_xor(t, 16);
        t += __shfl_xor(t, 32);
        if (lane < 16) sAbar[h][lane] = t;
    }
    __syncthreads();

    // ---- z (fp32 X): halves of tokens across rh ----
    {
        const int d = tid & 255, rh = tid >> 8;
        float zz[4] = {0.f, 0.f, 0.f, 0.f};
        #pragma unroll
        for (int t = 0; t < 8; ++t) {
            const int tok = rh * 8 + t;
            float xv = sXF[tok][d];
            #pragma unroll
            for (int h = 0; h < 4; ++h) zz[h] = fmaf(sAbar[h][tok], xv, zz[h]);
        }
        #pragma unroll
        for (int h = 0; h < 4; ++h) sZp[rh][h][d] = zz[h];
    }
    __syncthreads();

    const int n = tid & 255, g = tid >> 8, h = n >> 6;
    // ---- pp = z@Wv + cnt*bv (d-halves across g) ----
    {
        float pa = 0.f;
        for (int dc = 0; dc < 128; dc += 16) {
            float wv[16];
            #pragma unroll
            for (int q = 0; q < 16; ++q) wv[q] = Wv[(size_t)(g * 128 + dc + q) * 256 + n];
            #pragma unroll
            for (int q = 0; q < 16; ++q) {
                int dd = g * 128 + dc + q;
                pa = fmaf(sZp[0][h][dd] + sZp[1][h][dd], wv[q], pa);
            }
        }
        sHH[g][n] = pa;
    }
    __syncthreads();
    if (tid < 256) sPP[tid] = sHH[0][tid] + sHH[1][tid] + sCt * bv[tid];
    __syncthreads();
    // ---- out = pp@Wo/cnt + bo ----
    {
        float pa = 0.f;
        for (int dc = 0; dc < 128; dc += 16) {
            float wo[16];
            #pragma unroll
            for (int q = 0; q < 16; ++q) wo[q] = Wo[(size_t)(g * 128 + dc + q) * 256 + n];
            const float* pp = &sPP[g * 128 + dc];
            #pragma unroll
            for (int q = 0; q < 16; ++q) pa = fmaf(pp[q], wo[q], pa);
        }
        sHH[g][n] = pa;
    }
    __syncthreads();
    if (tid < 256) {
        float c = sCt;
        Out[(size_t)seq * 256 + tid] = (c > 0.f) ? ((sHH[0][tid] + sHH[1][tid]) / c + bo[tid]) : 0.f;
        if (MaskOut && tid == 0) MaskOut[seq] = (c > 0.f) ? 1.f : 0.f;
    }
}

extern "C" void kernel_launch(void* const* d_in, const int* in_sizes, int n_in,
                              void* d_out, int out_size, void* d_ws, size_t ws_size,
                              hipStream_t stream)
{
    const float* emb  = (const float*)d_in[0];
    const int*  amask = (const int*)d_in[1];
    const float* W[24];
    for (int i = 0; i < 24; ++i) W[i] = (const float*)d_in[2 + i];
    // W[0..7] = wWq,wWk,wWv,wWo,wbq,wbk,wbv,wbo ; W[8..15] = s* ; W[16..23] = c*

    char* ws = (char*)d_ws;
    unsigned short* WT = (unsigned short*)ws;        // 3 * 512*256 * 2B = 768KB
    float* zbuf  = (float*)(ws + 3 * 256 * 1024);    // 8MB
    float* cnt   = zbuf + 2048 * 1024;               // 8KB
    float* sent  = cnt + 2048;                       // 2MB
    float* smask = sent + 2048 * 256;                // 8KB
    float* sec   = smask + 2048;                     // 128KB
    float* cmask = sec + 128 * 256;                  // 512B
    float* out   = (float*)d_out;                    // 16*256

    prep_wt3<<<dim3(1536), dim3(256), 0, stream>>>(W[0], W[1], W[8], W[9], W[16], W[17], WT);

    // word level
    word_attn<<<dim3(2048), dim3(512), 0, stream>>>(emb, amask, WT, W[4], W[5], zbuf, cnt);
    apply2<<<dim3(256), dim3(512), 0, stream>>>(zbuf, cnt, W[2], W[3], W[6], W[7], sent, smask);

    // sentence level: 128 seqs of 16, one per block
    tail_kernel<16><<<dim3(128), dim3(512), 0, stream>>>(
        sent, smask, WT + 512 * 256, W[12], W[13], W[10], W[11], W[14], W[15], sec, cmask);

    // section level: 16 seqs of 8 (padded to 16), one per block
    tail_kernel<8><<<dim3(16), dim3(512), 0, stream>>>(
        sec, cmask, WT + 2 * 512 * 256, W[20], W[21], W[18], W[19], W[22], W[23], out, nullptr);
}

// Round 8
// 149.896 us; speedup vs baseline: 5.9251x; 1.0115x over previous
//
#include <hip/hip_runtime.h>

constexpr int D = 256;

typedef __attribute__((ext_vector_type(8))) __bf16 bf16x8;
typedef __attribute__((ext_vector_type(4))) float f32x4;
typedef __attribute__((ext_vector_type(16))) float f32x16;

__device__ inline unsigned short f2b(float f) {
    unsigned u = __builtin_bit_cast(unsigned, f);
    u = (u + 0x7fffu + ((u >> 16) & 1u)) >> 16;   // RNE
    return (unsigned short)u;
}
__device__ inline unsigned cvt_pk_bf16(float lo, float hi) {
    unsigned r;
    asm volatile("v_cvt_pk_bf16_f32 %0, %1, %2" : "=v"(r) : "v"(lo), "v"(hi));
    return r;
}
__device__ inline bf16x8 ld_frag(const void* p) {
    uint4 r = *(const uint4*)p;
    return __builtin_bit_cast(bf16x8, r);
}
// ---- DPP row_ror rotate-reduce across each 16-lane row (pure VALU, no LDS pipe) ----
template<int CTRL>
__device__ inline float dpp_f(float v) {
    return __builtin_bit_cast(float,
        __builtin_amdgcn_update_dpp(0, __builtin_bit_cast(int, v), CTRL, 0xf, 0xf, true));
}
__device__ inline float rsum16(float v) {
    v += dpp_f<0x121>(v);
    v += dpp_f<0x122>(v);
    v += dpp_f<0x124>(v);
    v += dpp_f<0x128>(v);
    return v;
}
__device__ inline float rmax16(float v) {
    v = fmaxf(v, dpp_f<0x121>(v));
    v = fmaxf(v, dpp_f<0x122>(v));
    v = fmaxf(v, dpp_f<0x124>(v));
    v = fmaxf(v, dpp_f<0x128>(v));
    return v;
}
constexpr float CE = 0.125f * 1.44269504f;   // 1/sqrt(dh) folded into exp2

// ---- prep (all 3 levels): WT[lvl][c][k] = bf16( c<256 ? Wq[k][c] : Wk[k][c-256] ) ----
__global__ void prep_wt3(const float* __restrict__ q0, const float* __restrict__ k0,
                         const float* __restrict__ q1, const float* __restrict__ k1,
                         const float* __restrict__ q2, const float* __restrict__ k2,
                         unsigned short* __restrict__ WT) {
    const int b = blockIdx.x, k = threadIdx.x;
    const int lvl = b >> 9, c = b & 511;
    const float* Wq = (lvl == 0) ? q0 : (lvl == 1) ? q1 : q2;
    const float* Wk = (lvl == 0) ? k0 : (lvl == 1) ? k1 : k2;
    const float* W = (c < 256) ? Wq : Wk;
    WT[(size_t)b * 256 + k] = f2b(W[k * 256 + (c & 255)]);
}

// ================== word level K1 (32x32x16 MFMA): 64 tokens / block ==================
__global__ __launch_bounds__(512, 4)
void word_attn(const float* __restrict__ X, const int* __restrict__ Mask,
               const unsigned short* __restrict__ WT,
               const float* __restrict__ bq, const float* __restrict__ bk,
               float* __restrict__ Zout, float* __restrict__ Cnt)
{
    __shared__ unsigned short sKX[64 * 256];  // 32KB: bf16 X -> bf16 K -> fp32 z partials
    __shared__ unsigned short sQ[64 * 256];   // 32KB: bf16 Q
    __shared__ float sM[64];
    __shared__ float sPart[8][64];
    __shared__ float sAbarT[64][4];
    __shared__ float sCt;

    const int tid = threadIdx.x;
    const int blk = blockIdx.x;
    const float* Xs = X + (size_t)blk * 64 * D;
    char* sKXb = (char*)sKX;
    char* sQb  = (char*)sQ;
    const int lane = tid & 63, w = tid >> 6;
    const int l31 = lane & 31, hi = lane >> 5;

    // ---- stage X -> bf16 LDS [64][256], pitch 512B, swizzle ((row&7)<<4); keep pk in regs ----
    uint2 pk[8];
    {
        const float4* X4 = (const float4*)Xs;
        float4 xv[8];
        #pragma unroll
        for (int j = 0; j < 8; ++j) xv[j] = X4[tid + j * 512];
        if (tid < 64) sM[tid] = (float)Mask[(size_t)blk * 64 + tid];
        #pragma unroll
        for (int j = 0; j < 8; ++j) {
            pk[j].x = cvt_pk_bf16(xv[j].x, xv[j].y);
            pk[j].y = cvt_pk_bf16(xv[j].z, xv[j].w);
            const int row = w + 8 * j;
            *(uint2*)(sKXb + row * 512 + ((lane * 8) ^ ((row & 7) << 4))) = pk[j];
        }
    }
    // pre-issue first WT fragments (L2) so their latency hides under the barrier drain
    // A-frag (32x32x16): row = feat w*64 + mf*32 + l31, k = kk*16 + hi*8
    const unsigned short* wtp = WT + (size_t)(w * 64 + l31) * 256 + hi * 8;
    bf16x8 a0[2], a1[2], b0[2], b1[2];
    a0[0] = ld_frag(wtp);
    a0[1] = ld_frag(wtp + 8192);     // mf=1 -> +32 feats * 256
    __syncthreads();
    if (tid < 64) {
        float v = sM[tid];
        #pragma unroll
        for (int o = 1; o < 64; o <<= 1) v += __shfl_xor(v, o);
        if (tid == 0) sCt = v;
    }

    // ---- proj': C[feature][token]; wave w owns feats w*64..+63 (Q: w<4, K: w>=4) ----
    f32x16 acc[2][2];
    {
        const float* bias = (w < 4) ? bq : bk;
        const int fb = (w & 3) * 64;
        #pragma unroll
        for (int mf = 0; mf < 2; ++mf)
            #pragma unroll
            for (int g = 0; g < 4; ++g) {
                float4 b4 = *(const float4*)(bias + fb + mf * 32 + 8 * g + 4 * hi);
                #pragma unroll
                for (int nt = 0; nt < 2; ++nt) {
                    acc[mf][nt][4 * g + 0] = b4.x;
                    acc[mf][nt][4 * g + 1] = b4.y;
                    acc[mf][nt][4 * g + 2] = b4.z;
                    acc[mf][nt][4 * g + 3] = b4.w;
                }
            }
        auto LDA = [&](bf16x8* d, int kkv) {
            d[0] = ld_frag(wtp + kkv * 16);
            d[1] = ld_frag(wtp + 8192 + kkv * 16);
        };
        auto LDB = [&](bf16x8* d, int kkv) {
            #pragma unroll
            for (int nt = 0; nt < 2; ++nt) {
                int t = nt * 32 + l31;
                d[nt] = ld_frag(sKXb + t * 512 + ((kkv * 32 + hi * 16) ^ ((t & 7) << 4)));
            }
        };
        auto MFMA4 = [&](bf16x8* a, bf16x8* b) {
            acc[0][0] = __builtin_amdgcn_mfma_f32_32x32x16_bf16(a[0], b[0], acc[0][0], 0, 0, 0);
            acc[0][1] = __builtin_amdgcn_mfma_f32_32x32x16_bf16(a[0], b[1], acc[0][1], 0, 0, 0);
            acc[1][0] = __builtin_amdgcn_mfma_f32_32x32x16_bf16(a[1], b[0], acc[1][0], 0, 0, 0);
            acc[1][1] = __builtin_amdgcn_mfma_f32_32x32x16_bf16(a[1], b[1], acc[1][1], 0, 0, 0);
        };
        LDB(b0, 0);
        #pragma unroll 1
        for (int kk = 0; kk < 16; kk += 2) {
            LDA(a1, kk + 1); LDB(b1, kk + 1);
            __builtin_amdgcn_s_setprio(1);
            MFMA4(a0, b0);
            __builtin_amdgcn_s_setprio(0);
            if (kk < 14) { LDA(a0, kk + 2); LDB(b0, kk + 2); }
            __builtin_amdgcn_s_setprio(1);
            MFMA4(a1, b1);
            __builtin_amdgcn_s_setprio(0);
        }
    }
    // ---- Q writeback (disjoint region, no hazard) BEFORE the X-protect barrier ----
    // C layout (32x32): col(token) = l31, row(feat-in-tile) = (r&3)+8*(r>>2)+4*hi
    auto WRITEBACK = [&](char* region) {
        #pragma unroll
        for (int nt = 0; nt < 2; ++nt) {
            const int t = nt * 32 + l31;
            char* rowp = region + t * 512;
            const int sw = (t & 7) << 4;
            #pragma unroll
            for (int mf = 0; mf < 2; ++mf)
                #pragma unroll
                for (int g = 0; g < 4; ++g) {
                    uint2 v;
                    v.x = cvt_pk_bf16(acc[mf][nt][4 * g + 0], acc[mf][nt][4 * g + 1]);
                    v.y = cvt_pk_bf16(acc[mf][nt][4 * g + 2], acc[mf][nt][4 * g + 3]);
                    const int fbyte = ((w & 3) * 64 + mf * 32 + 8 * g + 4 * hi) * 2;
                    *(uint2*)(rowp + (fbyte ^ sw)) = v;
                }
        }
    };
    if (w < 4) WRITEBACK(sQb);
    __syncthreads();                 // all X reads done
    if (w >= 4) WRITEBACK(sKXb);     // K overwrites X region
    __syncthreads();

    // ---- scores (32x32x16) + softmax + abar; wave w: head w>>1, query half w&1 ----
    {
        const int h = w >> 1, qh = w & 1;
        const int q = qh * 32 + l31;
        f32x16 sc0 = {}, sc1 = {};
        const int qsw = (q & 7) << 4;
        #pragma unroll
        for (int kk = 0; kk < 4; ++kk) {
            const int fby = h * 128 + kk * 32 + hi * 16;
            bf16x8 qa  = ld_frag(sQb + q * 512 + (fby ^ qsw));
            bf16x8 kb0 = ld_frag(sKXb + l31 * 512 + (fby ^ ((l31 & 7) << 4)));
            bf16x8 kb1 = ld_frag(sKXb + (32 + l31) * 512 + (fby ^ ((l31 & 7) << 4)));
            __builtin_amdgcn_s_setprio(1);
            sc0 = __builtin_amdgcn_mfma_f32_32x32x16_bf16(qa, kb0, sc0, 0, 0, 0);
            sc1 = __builtin_amdgcn_mfma_f32_32x32x16_bf16(qa, kb1, sc1, 0, 0, 0);
            __builtin_amdgcn_s_setprio(0);
        }
        const float mk0 = sM[l31], mk1 = sM[32 + l31];
        float pm0 = 0.f, pm1 = 0.f;
        #pragma unroll
        for (int r = 0; r < 16; ++r) {
            const int qrow = qh * 32 + (r & 3) + 8 * (r >> 2) + 4 * hi;
            float s0 = (mk0 > 0.f) ? sc0[r] : -1e9f;
            float s1 = (mk1 > 0.f) ? sc1[r] : -1e9f;
            float mx = fmaxf(s0, s1);
            mx = rmax16(mx);
            mx = fmaxf(mx, __shfl_xor(mx, 16));
            float e0 = __builtin_amdgcn_exp2f((s0 - mx) * CE);
            float e1 = __builtin_amdgcn_exp2f((s1 - mx) * CE);
            float se = rsum16(e0 + e1);
            se += __shfl_xor(se, 16);
            const float wr = sM[qrow] * __builtin_amdgcn_rcpf(se);
            pm0 += e0 * wr; pm1 += e1 * wr;
        }
        pm0 += __shfl_xor(pm0, 32);
        pm1 += __shfl_xor(pm1, 32);
        if (lane < 32) { sPart[w][lane] = pm0; sPart[w][32 + lane] = pm1; }
    }
    __syncthreads();
    // ---- abar token-major: consecutive tids -> stride-4-dword (2-way, free) ----
    if (tid < 256) {
        int h = tid >> 6, j = tid & 63;
        sAbarT[j][h] = sPart[2 * h][j] + sPart[2 * h + 1][j];
    }
    __syncthreads();

    // ---- z from held bf16-X regs: tokens w+8j, feats lane*4..+3 ----
    float zp[4][4];
    #pragma unroll
    for (int h = 0; h < 4; ++h)
        #pragma unroll
        for (int e = 0; e < 4; ++e) zp[h][e] = 0.f;
    #pragma unroll
    for (int j = 0; j < 8; ++j) {
        const int t = w + 8 * j;
        f32x4 ab = *(const f32x4*)&sAbarT[t][0];   // b128 broadcast (uniform per wave)
        float x0 = __builtin_bit_cast(float, pk[j].x << 16);
        float x1 = __builtin_bit_cast(float, pk[j].x & 0xffff0000u);
        float x2 = __builtin_bit_cast(float, pk[j].y << 16);
        float x3 = __builtin_bit_cast(float, pk[j].y & 0xffff0000u);
        #pragma unroll
        for (int h = 0; h < 4; ++h) {
            zp[h][0] = fmaf(ab[h], x0, zp[h][0]);
            zp[h][1] = fmaf(ab[h], x1, zp[h][1]);
            zp[h][2] = fmaf(ab[h], x2, zp[h][2]);
            zp[h][3] = fmaf(ab[h], x3, zp[h][3]);
        }
    }
    // ---- cross-wave reduce via [wave][head][256] in freed K region (32KB) ----
    float* zr = (float*)sKXb;
    #pragma unroll
    for (int h = 0; h < 4; ++h)
        *(f32x4*)&zr[(w * 4 + h) * 256 + lane * 4] =
            (f32x4){zp[h][0], zp[h][1], zp[h][2], zp[h][3]};
    __syncthreads();
    {
        const int d = tid & 255, hp = (tid >> 8) * 2;
        float a0 = 0.f, a1 = 0.f;
        #pragma unroll
        for (int ww = 0; ww < 8; ++ww) {
            a0 += zr[(ww * 4 + hp) * 256 + d];
            a1 += zr[(ww * 4 + hp + 1) * 256 + d];
        }
        float* Zo = Zout + (size_t)blk * 1024;
        Zo[hp * 256 + d] = a0;
        Zo[(hp + 1) * 256 + d] = a1;
    }
    if (tid == 0) Cnt[blk] = sCt;
}

// =============== apply2: pp = Z@Wv + cnt*bv ; out = pp@Wo/cnt + bo ===============
__global__ __launch_bounds__(512, 2)
void apply2(const float* __restrict__ Z, const float* __restrict__ Cnt,
            const float* __restrict__ Wv, const float* __restrict__ Wo,
            const float* __restrict__ bv, const float* __restrict__ bo,
            float* __restrict__ Out, float* __restrict__ MaskOut)
{
    constexpr int SPB = 8;
    __shared__ float sZ[SPB][4][256];
    __shared__ float sPP[SPB][256];
    __shared__ float sH[2][SPB][256];
    __shared__ float sCt[SPB];

    const int tid = threadIdx.x;
    const int s0 = blockIdx.x * SPB;
    {
        const float4* Zf = (const float4*)(Z + (size_t)s0 * 1024);
        float4* sZf = (float4*)sZ;
        #pragma unroll
        for (int k = 0; k < 4; ++k) sZf[tid + k * 512] = Zf[tid + k * 512];
        if (tid < SPB) sCt[tid] = Cnt[s0 + tid];
    }
    __syncthreads();

    const int n = tid & 255, g = tid >> 8, h = n >> 6;

    {
        float pa[SPB] = {};
        for (int dc = 0; dc < 128; dc += 16) {
            float wv[16];
            #pragma unroll
            for (int q = 0; q < 16; ++q) wv[q] = Wv[(size_t)(g * 128 + dc + q) * 256 + n];
            #pragma unroll
            for (int s = 0; s < SPB; ++s) {
                const float4* zp4 = (const float4*)&sZ[s][h][g * 128 + dc];
                #pragma unroll
                for (int q4 = 0; q4 < 4; ++q4) {
                    float4 zv = zp4[q4];
                    pa[s] = fmaf(zv.x, wv[q4 * 4 + 0], pa[s]);
                    pa[s] = fmaf(zv.y, wv[q4 * 4 + 1], pa[s]);
                    pa[s] = fmaf(zv.z, wv[q4 * 4 + 2], pa[s]);
                    pa[s] = fmaf(zv.w, wv[q4 * 4 + 3], pa[s]);
                }
            }
        }
        #pragma unroll
        for (int s = 0; s < SPB; ++s) sH[g][s][n] = pa[s];
    }
    __syncthreads();
    for (int i = tid; i < SPB * 256; i += 512) {
        int s = i >> 8, nn = i & 255;
        sPP[s][nn] = sH[0][s][nn] + sH[1][s][nn] + sCt[s] * bv[nn];
    }
    __syncthreads();
    {
        float pa[SPB] = {};
        for (int dc = 0; dc < 128; dc += 16) {
            float wo[16];
            #pragma unroll
            for (int q = 0; q < 16; ++q) wo[q] = Wo[(size_t)(g * 128 + dc + q) * 256 + n];
            #pragma unroll
            for (int s = 0; s < SPB; ++s) {
                const float4* pp = (const float4*)&sPP[s][g * 128 + dc];
                #pragma unroll
                for (int q4 = 0; q4 < 4; ++q4) {
                    float4 pv = pp[q4];
                    pa[s] = fmaf(pv.x, wo[q4 * 4 + 0], pa[s]);
                    pa[s] = fmaf(pv.y, wo[q4 * 4 + 1], pa[s]);
                    pa[s] = fmaf(pv.z, wo[q4 * 4 + 2], pa[s]);
                    pa[s] = fmaf(pv.w, wo[q4 * 4 + 3], pa[s]);
                }
            }
        }
        #pragma unroll
        for (int s = 0; s < SPB; ++s) sH[g][s][n] = pa[s];
    }
    __syncthreads();
    for (int i = tid; i < SPB * 256; i += 512) {
        int s = i >> 8, nn = i & 255;
        float c = sCt[s];
        Out[(size_t)(s0 + s) * 256 + nn] = (c > 0.f) ? ((sH[0][s][nn] + sH[1][s][nn]) / c + bo[nn]) : 0.f;
    }
    if (tid < SPB && MaskOut) MaskOut[s0 + tid] = (sCt[tid] > 0.f) ? 1.f : 0.f;
}

// ============ tail: ONE sequence (<=16 tokens, zero-padded) per block, fully fused ============
template<int LREAL>
__global__ __launch_bounds__(512, 2)
void tail_kernel(const float* __restrict__ X, const float* __restrict__ MaskIn,
                 const unsigned short* __restrict__ WT,
                 const float* __restrict__ bq, const float* __restrict__ bk,
                 const float* __restrict__ Wv, const float* __restrict__ Wo,
                 const float* __restrict__ bv, const float* __restrict__ bo,
                 float* __restrict__ Out, float* __restrict__ MaskOut)
{
    __shared__ unsigned short sX[16 * 256];   // 8KB bf16, pitch 512B, swizzled
    __shared__ unsigned short sQK[16 * 512];  // 16KB bf16, pitch 1024B, swizzled
    __shared__ float sXF[16][256];            // 16KB fp32 copy for z (exact numerics)
    __shared__ float sM[16];
    __shared__ float sAbar[4][16];
    __shared__ float sZp[2][4][256];          // 8KB
    __shared__ float sPP[256];
    __shared__ float sHH[2][256];
    __shared__ float sCt;

    const int tid = threadIdx.x;
    const int seq = blockIdx.x;
    const float* Xs = X + (size_t)seq * LREAL * 256;
    char* sBX = (char*)sX;
    char* sBQ = (char*)sQK;
    const int lane = tid & 63, w = tid >> 6;
    const int lr = lane & 15, lg = lane >> 4;

    // ---- stage (zero-pad rows >= LREAL) ----
    {
        const float4* X4 = (const float4*)Xs;
        #pragma unroll
        for (int j = 0; j < 2; ++j) {
            int idx = tid + j * 512;
            int row = idx >> 6, c4 = idx & 63;
            float4 v = (row < LREAL) ? X4[row * 64 + c4] : (float4){0.f, 0.f, 0.f, 0.f};
            uint2 p;
            p.x = cvt_pk_bf16(v.x, v.y);
            p.y = cvt_pk_bf16(v.z, v.w);
            *(uint2*)(sBX + row * 512 + ((c4 * 8) ^ ((row & 7) << 4))) = p;
            *(float4*)&sXF[row][c4 * 4] = v;
        }
        if (tid < 16) sM[tid] = (tid < LREAL) ? MaskIn[seq * LREAL + tid] : 0.f;
    }
    // pre-issue first WT fragments
    const unsigned short* wtp = WT + (size_t)(w * 64 + lr) * 256 + lg * 8;
    bf16x8 afn[4];
    #pragma unroll
    for (int m = 0; m < 4; ++m) afn[m] = ld_frag(wtp + m * 16 * 256);
    __syncthreads();
    if (tid < 64) {
        float v = (lane < LREAL) ? sM[lane] : 0.f;
        v = rsum16(v);
        if (lane == 0) sCt = v;
    }

    // ---- proj': wave w owns features w*64..+63 (Q: w<4, K: w>=4); single token tile ----
    f32x4 acc[4];
    {
        const float* bias = (w < 4) ? bq : bk;
        const int fb = (w & 3) * 64;
        #pragma unroll
        for (int m = 0; m < 4; ++m) {
            float4 b4 = *(const float4*)(bias + fb + m * 16 + lg * 4);
            acc[m] = (f32x4){b4.x, b4.y, b4.z, b4.w};
        }
        #pragma unroll 1
        for (int kk = 0; kk < 8; ++kk) {
            bf16x8 af[4];
            #pragma unroll
            for (int m = 0; m < 4; ++m) af[m] = afn[m];
            if (kk < 7) {
                #pragma unroll
                for (int m = 0; m < 4; ++m) afn[m] = ld_frag(wtp + m * 16 * 256 + (kk + 1) * 32);
            }
            bf16x8 bx = ld_frag(sBX + lr * 512 + ((kk * 64 + lg * 16) ^ ((lr & 7) << 4)));
            #pragma unroll
            for (int m = 0; m < 4; ++m)
                acc[m] = __builtin_amdgcn_mfma_f32_16x16x32_bf16(af[m], bx, acc[m], 0, 0, 0);
        }
    }
    // ---- writeback: thread holds token lr, feats w*64+m*16+lg*4+r ----
    #pragma unroll
    for (int m = 0; m < 4; ++m) {
        uint2 qk;
        qk.x = cvt_pk_bf16(acc[m][0], acc[m][1]);
        qk.y = cvt_pk_bf16(acc[m][2], acc[m][3]);
        *(uint2*)(sBQ + lr * 1024 + ((w * 128 + m * 32 + lg * 8) ^ ((lr & 7) << 4))) = qk;
    }
    __syncthreads();

    // ---- scores + softmax + abar: wave h (<4) does head h's 16x16 tile ----
    if (w < 4) {
        const int h = w;
        f32x4 sacc = (f32x4){0.f, 0.f, 0.f, 0.f};
        #pragma unroll
        for (int kk = 0; kk < 2; ++kk) {
            bf16x8 qf = ld_frag(sBQ + lr * 1024 + ((h * 128 + kk * 64 + lg * 16) ^ ((lr & 7) << 4)));
            bf16x8 kf = ld_frag(sBQ + lr * 1024 + ((512 + h * 128 + kk * 64 + lg * 16) ^ ((lr & 7) << 4)));
            sacc = __builtin_amdgcn_mfma_f32_16x16x32_bf16(qf, kf, sacc, 0, 0, 0);
        }
        const float mkey = sM[lr];
        float t = 0.f;
        #pragma unroll
        for (int r = 0; r < 4; ++r) {
            const int qi = lg * 4 + r;
            float s = (mkey > 0.f) ? sacc[r] : -1e9f;
            float mx = rmax16(s);
            float e = __builtin_amdgcn_exp2f((s - mx) * CE);
            float se = rsum16(e);
            t += e * (sM[qi] * __builtin_amdgcn_rcpf(se));   // m_qi * a[qi][lr]
        }
        t += __shfl_xor(t, 16);
        t += __shfl_xor(t, 32);
        if (lane < 16) sAbar[h][lane] = t;
    }
    __syncthreads();

    // ---- z (fp32 X): halves of tokens across rh ----
    {
        const int d = tid & 255, rh = tid >> 8;
        float zz[4] = {0.f, 0.f, 0.f, 0.f};
        #pragma unroll
        for (int t = 0; t < 8; ++t) {
            const int tok = rh * 8 + t;
            float xv = sXF[tok][d];
            #pragma unroll
            for (int h = 0; h < 4; ++h) zz[h] = fmaf(sAbar[h][tok], xv, zz[h]);
        }
        #pragma unroll
        for (int h = 0; h < 4; ++h) sZp[rh][h][d] = zz[h];
    }
    __syncthreads();

    const int n = tid & 255, g = tid >> 8, h = n >> 6;
    // ---- pp = z@Wv + cnt*bv (d-halves across g) ----
    {
        float pa = 0.f;
        for (int dc = 0; dc < 128; dc += 16) {
            float wv[16];
            #pragma unroll
            for (int q = 0; q < 16; ++q) wv[q] = Wv[(size_t)(g * 128 + dc + q) * 256 + n];
            #pragma unroll
            for (int q = 0; q < 16; ++q) {
                int dd = g * 128 + dc + q;
                pa = fmaf(sZp[0][h][dd] + sZp[1][h][dd], wv[q], pa);
            }
        }
        sHH[g][n] = pa;
    }
    __syncthreads();
    if (tid < 256) sPP[tid] = sHH[0][tid] + sHH[1][tid] + sCt * bv[tid];
    __syncthreads();
    // ---- out = pp@Wo/cnt + bo ----
    {
        float pa = 0.f;
        for (int dc = 0; dc < 128; dc += 16) {
            float wo[16];
            #pragma unroll
            for (int q = 0; q < 16; ++q) wo[q] = Wo[(size_t)(g * 128 + dc + q) * 256 + n];
            const float* pp = &sPP[g * 128 + dc];
            #pragma unroll
            for (int q = 0; q < 16; ++q) pa = fmaf(pp[q], wo[q], pa);
        }
        sHH[g][n] = pa;
    }
    __syncthreads();
    if (tid < 256) {
        float c = sCt;
        Out[(size_t)seq * 256 + tid] = (c > 0.f) ? ((sHH[0][tid] + sHH[1][tid]) / c + bo[tid]) : 0.f;
        if (MaskOut && tid == 0) MaskOut[seq] = (c > 0.f) ? 1.f : 0.f;
    }
}

extern "C" void kernel_launch(void* const* d_in, const int* in_sizes, int n_in,
                              void* d_out, int out_size, void* d_ws, size_t ws_size,
                              hipStream_t stream)
{
    const float* emb  = (const float*)d_in[0];
    const int*  amask = (const int*)d_in[1];
    const float* W[24];
    for (int i = 0; i < 24; ++i) W[i] = (const float*)d_in[2 + i];
    // W[0..7] = wWq,wWk,wWv,wWo,wbq,wbk,wbv,wbo ; W[8..15] = s* ; W[16..23] = c*

    char* ws = (char*)d_ws;
    unsigned short* WT = (unsigned short*)ws;        // 3 * 512*256 * 2B = 768KB
    float* zbuf  = (float*)(ws + 3 * 256 * 1024);    // 8MB
    float* cnt   = zbuf + 2048 * 1024;               // 8KB
    float* sent  = cnt + 2048;                       // 2MB
    float* smask = sent + 2048 * 256;                // 8KB
    float* sec   = smask + 2048;                     // 128KB
    float* cmask = sec + 128 * 256;                  // 512B
    float* out   = (float*)d_out;                    // 16*256

    prep_wt3<<<dim3(1536), dim3(256), 0, stream>>>(W[0], W[1], W[8], W[9], W[16], W[17], WT);

    // word level
    word_attn<<<dim3(2048), dim3(512), 0, stream>>>(emb, amask, WT, W[4], W[5], zbuf, cnt);
    apply2<<<dim3(256), dim3(512), 0, stream>>>(zbuf, cnt, W[2], W[3], W[6], W[7], sent, smask);

    // sentence level: 128 seqs of 16, one per block
    tail_kernel<16><<<dim3(128), dim3(512), 0, stream>>>(
        sent, smask, WT + 512 * 256, W[12], W[13], W[10], W[11], W[14], W[15], sec, cmask);

    // section level: 16 seqs of 8 (padded to 16), one per block
    tail_kernel<8><<<dim3(16), dim3(512), 0, stream>>>(
        sec, cmask, WT + 2 * 512 * 256, W[20], W[21], W[18], W[19], W[22], W[23], out, nullptr);
}